// Round 6
// baseline (214.707 us; speedup 1.0000x reference)
//
#include <hip/hip_runtime.h>

#define NHEADS 12
#define SEQ    1024
#define HDIM   768
#define DHEAD  64
#define BH_TOT 48
#define EPSN   1e-6f

typedef __attribute__((ext_vector_type(8))) short    bf8;  // 8 bf16 (4 VGPRs) MFMA A/B frag
typedef __attribute__((ext_vector_type(4))) float    fx4;  // MFMA C/D frag / float4
typedef __attribute__((ext_vector_type(4))) _Float16 h4;   // 4 f16 (2 VGPRs) 16x16x16 frag

#define SZT 3145728u   // 48*1024*64 elements (one head-split tensor)
#define WSZ 589824u    // 768*768 elements (one weight matrix)

__device__ __forceinline__ float bf2f(unsigned short h) {
  union { unsigned int u; float f; } v; v.u = ((unsigned int)h) << 16; return v.f;
}
__device__ __forceinline__ unsigned short f2bf(float f) {
  union { float f; unsigned int u; } v; v.f = f;
  unsigned int u = v.u;
  return (unsigned short)((u + 0x7FFFu + ((u >> 16) & 1u)) >> 16);
}

// async global->LDS, 16B per lane; LDS dest = wave-uniform base + lane*16.
typedef __attribute__((address_space(3))) unsigned int lds_u32;
typedef __attribute__((address_space(1))) const unsigned int glb_u32;
__device__ __forceinline__ void gld16(const unsigned short* g, unsigned short* l) {
  __builtin_amdgcn_global_load_lds((glb_u32*)g, (lds_u32*)l, 16, 0, 0);
}

// ---------------------------------------------------------------------------
// One-shot f32 -> bf16 conversion of X (hs,te,se) and W (q,k,v,t,s) into ws.
// Layout (ushort units): hsb@5SZ teb@6SZ seb@7SZ  W[z]@8SZ + z*WSZ
// ---------------------------------------------------------------------------
__global__ void convert_kernel(const float* __restrict__ hs, const float* __restrict__ te,
                               const float* __restrict__ se,
                               const float* __restrict__ Wq, const float* __restrict__ Wk,
                               const float* __restrict__ Wv, const float* __restrict__ Wt,
                               const float* __restrict__ Ws2,
                               unsigned short* __restrict__ ws)
{
  const int z = blockIdx.y;
  const float* src;
  unsigned short* dst;
  int n;
  if (z < 3) {
    src = (z == 0) ? hs : (z == 1) ? te : se;
    dst = ws + (size_t)(5 + z) * SZT;
    n = 3145728;
  } else {
    src = (z == 3) ? Wq : (z == 4) ? Wk : (z == 5) ? Wv : (z == 6) ? Wt : Ws2;
    dst = ws + (size_t)8 * SZT + (size_t)(z - 3) * WSZ;
    n = 589824;
  }
  const int base = (blockIdx.x * 256 + threadIdx.x) * 8;
  if (base >= n) return;
  const fx4 a = *(const fx4*)(src + base);
  const fx4 b = *(const fx4*)(src + base + 4);
  bf8 o;
#pragma unroll
  for (int j = 0; j < 4; ++j) { o[j] = (short)f2bf(a[j]); o[4 + j] = (short)f2bf(b[j]); }
  *(bf8*)(dst + base) = o;
}

// ---------------------------------------------------------------------------
// Projection GEMM (bf16 in): out = X[4096,768] @ W[768,768]^T + b, head-split.
// Unfused 5-z (960 blocks, ~3/CU). Double-buffered gld16 staging, one barrier
// per K-tile. z: 0=Q 1=K 2=V(f16, transposed Vt[bh*64+d][1024]) 3=T 4=S
// ---------------------------------------------------------------------------
__global__ __launch_bounds__(256, 3)
void proj_kernel(unsigned short* __restrict__ ws,
                 const float* __restrict__ bq, const float* __restrict__ bk,
                 const float* __restrict__ bv, const float* __restrict__ bt,
                 const float* __restrict__ bs)
{
  __shared__ unsigned short Xs[2][4096];
  __shared__ unsigned short Ys[2][4096];

  const int z = blockIdx.z;
  const unsigned short* X = ws + (size_t)5 * SZT + (size_t)((z < 3) ? 0 : (z - 2)) * SZT;
  const unsigned short* W = ws + (size_t)8 * SZT + (size_t)z * WSZ;
  const float* bias = (z == 0) ? bq : (z == 1) ? bk : (z == 2) ? bv : (z == 3) ? bt : bs;
  unsigned short* out = ws + (size_t)((z < 2) ? z : (z == 2) ? 4 : (z == 3) ? 2 : 3) * SZT;

  const int tid   = threadIdx.x;
  const int lane  = tid & 63;
  const int wid   = tid >> 6;
  const int wm    = wid >> 1, wn = wid & 1;
  const int colid = lane & 15, quad = lane >> 4;
  const int m0 = blockIdx.y * 128, n0 = blockIdx.x * 128;

  auto stage = [&](int kt, int pb) {
#pragma unroll
    for (int i = 0; i < 2; ++i) {
      const int slot = i * 256 + tid;        // 0..511, 16B each
      const int row = slot >> 2, ch = slot & 3;
      gld16(X + (m0 + row) * HDIM + kt + ch * 8, &Xs[pb][slot * 8]);
      gld16(W + (n0 + row) * HDIM + kt + ch * 8, &Ys[pb][slot * 8]);
    }
  };

  fx4 acc[4][4];
#pragma unroll
  for (int i = 0; i < 4; ++i)
#pragma unroll
    for (int j = 0; j < 4; ++j) acc[i][j] = (fx4){0.f, 0.f, 0.f, 0.f};

  stage(0, 0);
  __syncthreads();

  for (int it = 0; it < 24; ++it) {
    const int pb = it & 1;
    if (it + 1 < 24) stage((it + 1) * 32, pb ^ 1);

    bf8 af[4], bfr[4];
#pragma unroll
    for (int i = 0; i < 4; ++i)
      af[i] = *(const bf8*)&Xs[pb][(wm * 64 + i * 16 + colid) * 32 + quad * 8];
#pragma unroll
    for (int j = 0; j < 4; ++j)
      bfr[j] = *(const bf8*)&Ys[pb][(wn * 64 + j * 16 + colid) * 32 + quad * 8];
#pragma unroll
    for (int i = 0; i < 4; ++i)
#pragma unroll
      for (int j = 0; j < 4; ++j)
        acc[i][j] = __builtin_amdgcn_mfma_f32_16x16x32_bf16(af[i], bfr[j], acc[i][j], 0, 0, 0);
    __syncthreads();
  }

  // Epilogue. C/D layout: col=lane&15, row=quad*4+reg.
  if (z != 2) {
#pragma unroll
    for (int i = 0; i < 4; ++i) {
      const int r0 = m0 + wm * 64 + i * 16 + quad * 4;
      const int bb = r0 >> 10, s0 = r0 & 1023;
#pragma unroll
      for (int j = 0; j < 4; ++j) {
        const int c = n0 + wn * 64 + j * 16 + colid;
        const int h = c >> 6, d = c & 63;
        const float bvl = bias[c];
        unsigned short* op = out + (((bb * NHEADS + h) * SEQ + s0) * DHEAD + d);
#pragma unroll
        for (int reg = 0; reg < 4; ++reg)
          op[reg * DHEAD] = f2bf(acc[i][j][reg] + bvl);
      }
    }
  } else {
    // V -> f16, transposed: Vt[(bh*64+d)*1024 + s], 4 consecutive s per 8B store.
#pragma unroll
    for (int i = 0; i < 4; ++i) {
      const int r0 = m0 + wm * 64 + i * 16 + quad * 4;
      const int bb = r0 >> 10, s0 = r0 & 1023;
#pragma unroll
      for (int j = 0; j < 4; ++j) {
        const int c = n0 + wn * 64 + j * 16 + colid;
        const int h = c >> 6, d = c & 63;
        const float bvl = bias[c];
        h4 pk;
#pragma unroll
        for (int reg = 0; reg < 4; ++reg)
          pk[reg] = (_Float16)(acc[i][j][reg] + bvl);
        *(h4*)(void*)(out + ((size_t)((bb * NHEADS + h) * DHEAD + d)) * SEQ + s0) = pk;
      }
    }
  }
}

// ---------------------------------------------------------------------------
// Flash attention. Round 12: in-block split-K with 4-wave blocks.
// Ladder: r3 (4w x 32q, grid 384 = 1.5 blk/CU) = 60.6us best, limited by
// makespan imbalance. r5 (2w blocks, grid 768) = 72us: staging per thread
// 1.5x r3 and residency stuck at 2.3 blk/CU. This round: block = 4 waves;
// waves 0,1 = q[q0,q0+64) x keys [0,512); waves 2,3 = same q x keys
// [512,1024). Grid = 48bh x 16 qtiles = 768 = EXACTLY 3 blocks/CU, per-wave
// AI unchanged (32q, law r1/r4), staging 96 gld16/thread (vs r3 128, r5 192).
// Stage unit = 32-key tile PAIR (one per key-half), 24KB, dbuf 48KB -> 3/CU.
// Partial (m,l,O) merged in-block via r2's verified combine, LDS aliased
// into the staging buffer after the final barrier (no extra LDS).
// V via per-wave global h4 loads; 12 waves/CU hide it.
// ---------------------------------------------------------------------------
__global__ __launch_bounds__(256, 3)
void attn_kernel(const unsigned short* __restrict__ ws,
                 const float* __restrict__ maskb,
                 float* __restrict__ outb)
{
  const unsigned short* Qb  = ws;
  const unsigned short* GT0 = ws + (size_t)1 * SZT;   // K
  const unsigned short* GT1 = ws + (size_t)2 * SZT;   // T
  const unsigned short* GT2 = ws + (size_t)3 * SZT;   // S
  const _Float16* Vtf = (const _Float16*)(ws + (size_t)4 * SZT);

  __shared__ unsigned short Ls[2][2][3][32][64];  // 48 KB [buf][khalf][K,T,S][key][d]

  const int tid   = threadIdx.x;
  const int lane  = tid & 63;
  const int wid   = tid >> 6;          // 0..3
  const int wq    = wid & 1;           // q-subtile within block
  const int wp    = wid >> 1;          // key half (0: [0,512), 1: [512,1024))
  const int colid = lane & 15, quad = lane >> 4;

  // XCD swizzle: 768 blocks; lin&7 = XCD; each XCD owns 6 bh entirely.
  const int lin = blockIdx.x;
  const int xcd = lin & 7;
  const int idx = lin >> 3;            // 0..95
  const int bh  = xcd * 6 + (idx % 6);
  const int qx  = idx / 6;             // 0..15
  const int b   = bh / NHEADS, h = bh % NHEADS;
  const int q0  = qx * 64 + wq * 32;
  const int base_h = bh * SEQ * DHEAD;
  const int kbase  = wp * 512;

  // Query-side B-frags for 2 q-groups: lane holds B[k=quad*8+j][n=colid].
  bf8 bqf[2][2], btf[2][2], bsf[2][2];
  float rs[2];
#pragma unroll
  for (int g = 0; g < 2; ++g) {
    const int row = q0 + g * 16 + colid;
    const unsigned short* qp = Qb  + base_h + row * 64 + quad * 8;
    const unsigned short* tp = GT1 + base_h + row * 64 + quad * 8;
    const unsigned short* sp = GT2 + base_h + row * 64 + quad * 8;
    bqf[g][0] = *(const bf8*)qp;  bqf[g][1] = *(const bf8*)(qp + 32);
    btf[g][0] = *(const bf8*)tp;  btf[g][1] = *(const bf8*)(tp + 32);
    bsf[g][0] = *(const bf8*)sp;  bsf[g][1] = *(const bf8*)(sp + 32);
    float t2 = 0.f, s2 = 0.f;
#pragma unroll
    for (int fr = 0; fr < 2; ++fr)
#pragma unroll
      for (int j = 0; j < 8; ++j) {
        const float tv = bf2f((unsigned short)btf[g][fr][j]);
        const float sv2 = bf2f((unsigned short)bsf[g][fr][j]);
        t2 += tv * tv; s2 += sv2 * s2 * 0.f + sv2 * sv2;
      }
    t2 += __shfl_xor(t2, 16); t2 += __shfl_xor(t2, 32);
    s2 += __shfl_xor(s2, 16); s2 += __shfl_xor(s2, 32);
    rs[g] = 1.0f / ((sqrtf(t2) + EPSN) * (sqrtf(s2) + EPSN) * 8.0f);
  }

  // Stage one 32-key tile PAIR (low half t*32, high half 512+t*32): K,T,S,
  // 1536 slots of 16B over 256 threads = 6 gld16/thread. Slot map: i<3 ->
  // pair 0, i>=3 -> pair 1; tensor = i%3; row = tid>>3 (0..31); colslot =
  // tid&7, global source pre-swizzled by ^(row&7).
  auto stage = [&](int t, int pb) {
#pragma unroll
    for (int i = 0; i < 6; ++i) {
      const int p  = (i >= 3) ? 1 : 0;
      const int tz = i - p * 3;
      const int kb = p * 512 + t * 32;
      const int r  = tid >> 3;
      const int cs = ((tid & 7) ^ (r & 7)) * 8;
      unsigned short* dst = &Ls[pb][0][0][0][0] + (size_t)(i * 256 + tid) * 8;
      const unsigned short* src =
          ((tz == 0) ? GT0 : (tz == 1) ? GT1 : GT2) + base_h + (kb + r) * 64 + cs;
      gld16(src, dst);
    }
  };

  float m_[2], l_[2];
  fx4 o[2][4];
#pragma unroll
  for (int g = 0; g < 2; ++g) {
    m_[g] = -1.0e30f; l_[g] = 0.f;
#pragma unroll
    for (int fd = 0; fd < 4; ++fd) o[g][fd] = (fx4){0.f, 0.f, 0.f, 0.f};
  }
  const fx4 zero = (fx4){0.f, 0.f, 0.f, 0.f};

  stage(0, 0);
  __syncthreads();

#pragma unroll 1
  for (int t = 0; t < 16; ++t) {
    const int pb = t & 1;
    if (t + 1 < 16) stage(t + 1, pb ^ 1);
    const int kb = kbase + t * 32;

    // ---- this wave's 32-key half: K/T/S frags from LDS, V + mask global ----
    bf8 ak[2][2], at_[2][2], as_[2][2];
    h4 vv[2][4];
    fx4 mk[2];
#pragma unroll
    for (int ff = 0; ff < 2; ++ff) {
      const int row = ff * 16 + colid;
      const int sw  = row & 7;
#pragma unroll
      for (int fr = 0; fr < 2; ++fr) {
        const int co = ((quad + fr * 4) ^ sw) * 8;
        ak[ff][fr]  = *(const bf8*)&Ls[pb][wp][0][row][co];
        at_[ff][fr] = *(const bf8*)&Ls[pb][wp][1][row][co];
        as_[ff][fr] = *(const bf8*)&Ls[pb][wp][2][row][co];
      }
#pragma unroll
      for (int fd = 0; fd < 4; ++fd)
        vv[ff][fd] = *(const h4*)(Vtf + (size_t)(bh * DHEAD + fd * 16 + colid) * SEQ
                                      + kb + ff * 16 + quad * 4);
      mk[ff] = *(const fx4*)(maskb + b * SEQ + kb + ff * 16 + quad * 4);
    }

    // ---- per q-group: scores^T, online softmax over 32 keys, PV ----
#pragma unroll
    for (int g = 0; g < 2; ++g) {
      float sv[2][4];
#pragma unroll
      for (int ff = 0; ff < 2; ++ff) {
        fx4 ab = __builtin_amdgcn_mfma_f32_16x16x32_bf16(ak[ff][0], bqf[g][0], zero, 0, 0, 0);
        ab = __builtin_amdgcn_mfma_f32_16x16x32_bf16(ak[ff][1], bqf[g][1], ab, 0, 0, 0);
        fx4 tt = __builtin_amdgcn_mfma_f32_16x16x32_bf16(at_[ff][0], btf[g][0], zero, 0, 0, 0);
        tt = __builtin_amdgcn_mfma_f32_16x16x32_bf16(at_[ff][1], btf[g][1], tt, 0, 0, 0);
        fx4 ss = __builtin_amdgcn_mfma_f32_16x16x32_bf16(as_[ff][0], bsf[g][0], zero, 0, 0, 0);
        ss = __builtin_amdgcn_mfma_f32_16x16x32_bf16(as_[ff][1], bsf[g][1], ss, 0, 0, 0);
#pragma unroll
        for (int reg = 0; reg < 4; ++reg)
          sv[ff][reg] = (ab[reg] * tt[reg]) * ss[reg] * rs[g] + mk[ff][reg];
      }

      float bm = sv[0][0];
#pragma unroll
      for (int ff = 0; ff < 2; ++ff)
#pragma unroll
        for (int reg = 0; reg < 4; ++reg) bm = fmaxf(bm, sv[ff][reg]);
      bm = fmaxf(bm, __shfl_xor(bm, 16));
      bm = fmaxf(bm, __shfl_xor(bm, 32));
      const float mn = fmaxf(m_[g], bm);
      const float alpha = __expf(m_[g] - mn);
      float rsum = 0.f;
      h4 pa[2];
#pragma unroll
      for (int ff = 0; ff < 2; ++ff)
#pragma unroll
        for (int reg = 0; reg < 4; ++reg) {
          const float p = __expf(sv[ff][reg] - mn);
          rsum += p;
          pa[ff][reg] = (_Float16)p;
        }
      rsum += __shfl_xor(rsum, 16);
      rsum += __shfl_xor(rsum, 32);
      l_[g] = l_[g] * alpha + rsum;
      m_[g] = mn;

      float ar[4];
#pragma unroll
      for (int reg = 0; reg < 4; ++reg) ar[reg] = __shfl(alpha, quad * 4 + reg);
#pragma unroll
      for (int fd = 0; fd < 4; ++fd)
#pragma unroll
        for (int reg = 0; reg < 4; ++reg) o[g][fd][reg] *= ar[reg];

#pragma unroll
      for (int ff = 0; ff < 2; ++ff)
#pragma unroll
        for (int fd = 0; fd < 4; ++fd)
          o[g][fd] = __builtin_amdgcn_mfma_f32_16x16x16f16(pa[ff], vv[ff][fd], o[g][fd], 0, 0, 0);
    }
    __syncthreads();
  }

  // ---- in-block split-K combine: waves 2,3 publish into LDS (aliased over
  // the staging buffer, safe after the final loop barrier); waves 0,1 merge
  // with their partner (wid+2) and write out. Layout: Lo[w2][g][fd][reg][lane]
  // (16 KB) then Lm[w2][g][16], Ll[w2][g][16].
  float* Lsf = (float*)&Ls[0][0][0][0][0];
  if (wid >= 2) {
    const int w2 = wid - 2;
#pragma unroll
    for (int g = 0; g < 2; ++g) {
#pragma unroll
      for (int fd = 0; fd < 4; ++fd)
#pragma unroll
        for (int reg = 0; reg < 4; ++reg)
          Lsf[((((w2 * 2 + g) * 4 + fd) * 4 + reg) * 64) + lane] = o[g][fd][reg];
      if (quad == 0) {
        Lsf[4096 + (w2 * 2 + g) * 16 + colid] = m_[g];
        Lsf[4096 + 64 + (w2 * 2 + g) * 16 + colid] = l_[g];
      }
    }
  }
  __syncthreads();
  if (wid < 2) {
    const int w2 = wid;
#pragma unroll
    for (int g = 0; g < 2; ++g) {
      const float m1v = Lsf[4096 + (w2 * 2 + g) * 16 + colid];
      const float l1v = Lsf[4096 + 64 + (w2 * 2 + g) * 16 + colid];
      const float M   = fmaxf(m_[g], m1v);
      const float a0  = __expf(m_[g] - M), a1 = __expf(m1v - M);
      const float li  = 1.0f / (l_[g] * a0 + l1v * a1);
      const float c0 = a0 * li, c1 = a1 * li;
      float s0[4], s1[4];
#pragma unroll
      for (int reg = 0; reg < 4; ++reg) {
        s0[reg] = __shfl(c0, quad * 4 + reg);
        s1[reg] = __shfl(c1, quad * 4 + reg);
      }
#pragma unroll
      for (int reg = 0; reg < 4; ++reg) {
        const int s = q0 + g * 16 + quad * 4 + reg;
#pragma unroll
        for (int fd = 0; fd < 4; ++fd) {
          const float val = o[g][fd][reg] * s0[reg]
                          + Lsf[((((w2 * 2 + g) * 4 + fd) * 4 + reg) * 64) + lane] * s1[reg];
          outb[(size_t)(b * SEQ + s) * HDIM + h * DHEAD + fd * 16 + colid] = val;
        }
      }
    }
  }
}

extern "C" void kernel_launch(void* const* d_in, const int* in_sizes, int n_in,
                              void* d_out, int out_size, void* d_ws, size_t ws_size,
                              hipStream_t stream)
{
  (void)in_sizes; (void)n_in; (void)out_size; (void)ws_size;
  const float* hs   = (const float*)d_in[0];
  const float* te   = (const float*)d_in[1];
  const float* se   = (const float*)d_in[2];
  const float* mask = (const float*)d_in[3];
  const float* Wq   = (const float*)d_in[4];
  const float* bq   = (const float*)d_in[5];
  const float* Wk   = (const float*)d_in[6];
  const float* bk   = (const float*)d_in[7];
  const float* Wv   = (const float*)d_in[8];
  const float* bv   = (const float*)d_in[9];
  const float* Wt   = (const float*)d_in[10];
  const float* bt   = (const float*)d_in[11];
  const float* Wsp  = (const float*)d_in[12];
  const float* bsp  = (const float*)d_in[13];
  float* out = (float*)d_out;
  unsigned short* ws = (unsigned short*)d_ws;

  // ws layout (ushort units): Qb@0 Kb@1SZ Tb@2SZ Sb@3SZ Vt(f16)@4SZ
  // convert-phase: hsb@5SZ teb@6SZ seb@7SZ W[5]@8SZ+z*WSZ (dead after proj)
  convert_kernel<<<dim3(1536, 8), 256, 0, stream>>>(hs, te, se, Wq, Wk, Wv, Wt, Wsp, ws);
  proj_kernel<<<dim3(6, 32, 5), 256, 0, stream>>>(ws, bq, bk, bv, bt, bsp);
  attn_kernel<<<dim3(768), 256, 0, stream>>>(ws, mask, out);
}

// Round 7
// 205.204 us; speedup vs baseline: 1.0463x; 1.0463x over previous
//
#include <hip/hip_runtime.h>

#define NHEADS 12
#define SEQ    1024
#define HDIM   768
#define DHEAD  64
#define BH_TOT 48
#define EPSN   1e-6f

typedef __attribute__((ext_vector_type(8))) short    bf8;  // 8 bf16 (4 VGPRs) MFMA A/B frag
typedef __attribute__((ext_vector_type(4))) float    fx4;  // MFMA C/D frag / float4
typedef __attribute__((ext_vector_type(4))) _Float16 h4;   // 4 f16 (2 VGPRs) 16x16x16 frag

#define SZT 3145728u   // 48*1024*64 elements (one head-split tensor)
#define WSZ 589824u    // 768*768 elements (one weight matrix)

__device__ __forceinline__ float bf2f(unsigned short h) {
  union { unsigned int u; float f; } v; v.u = ((unsigned int)h) << 16; return v.f;
}
__device__ __forceinline__ unsigned short f2bf(float f) {
  union { float f; unsigned int u; } v; v.f = f;
  unsigned int u = v.u;
  return (unsigned short)((u + 0x7FFFu + ((u >> 16) & 1u)) >> 16);
}

// async global->LDS, 16B per lane; LDS dest = wave-uniform base + lane*16.
typedef __attribute__((address_space(3))) unsigned int lds_u32;
typedef __attribute__((address_space(1))) const unsigned int glb_u32;
__device__ __forceinline__ void gld16(const unsigned short* g, unsigned short* l) {
  __builtin_amdgcn_global_load_lds((glb_u32*)g, (lds_u32*)l, 16, 0, 0);
}

// ---------------------------------------------------------------------------
// One-shot f32 -> bf16 conversion of X (hs,te,se) and W (q,k,v,t,s) into ws.
// Layout (ushort units): hsb@5SZ teb@6SZ seb@7SZ  W[z]@8SZ + z*WSZ
// ---------------------------------------------------------------------------
__global__ void convert_kernel(const float* __restrict__ hs, const float* __restrict__ te,
                               const float* __restrict__ se,
                               const float* __restrict__ Wq, const float* __restrict__ Wk,
                               const float* __restrict__ Wv, const float* __restrict__ Wt,
                               const float* __restrict__ Ws2,
                               unsigned short* __restrict__ ws)
{
  const int z = blockIdx.y;
  const float* src;
  unsigned short* dst;
  int n;
  if (z < 3) {
    src = (z == 0) ? hs : (z == 1) ? te : se;
    dst = ws + (size_t)(5 + z) * SZT;
    n = 3145728;
  } else {
    src = (z == 3) ? Wq : (z == 4) ? Wk : (z == 5) ? Wv : (z == 6) ? Wt : Ws2;
    dst = ws + (size_t)8 * SZT + (size_t)(z - 3) * WSZ;
    n = 589824;
  }
  const int base = (blockIdx.x * 256 + threadIdx.x) * 8;
  if (base >= n) return;
  const fx4 a = *(const fx4*)(src + base);
  const fx4 b = *(const fx4*)(src + base + 4);
  bf8 o;
#pragma unroll
  for (int j = 0; j < 4; ++j) { o[j] = (short)f2bf(a[j]); o[4 + j] = (short)f2bf(b[j]); }
  *(bf8*)(dst + base) = o;
}

// ---------------------------------------------------------------------------
// Projection GEMM (bf16 in): out = X[4096,768] @ W[768,768]^T + b, head-split.
// Unfused 5-z (960 blocks, ~3/CU). Double-buffered gld16 staging, one barrier
// per K-tile. z: 0=Q 1=K 2=V(f16, transposed Vt[bh*64+d][1024]) 3=T 4=S
// ---------------------------------------------------------------------------
__global__ __launch_bounds__(256, 3)
void proj_kernel(unsigned short* __restrict__ ws,
                 const float* __restrict__ bq, const float* __restrict__ bk,
                 const float* __restrict__ bv, const float* __restrict__ bt,
                 const float* __restrict__ bs)
{
  __shared__ unsigned short Xs[2][4096];
  __shared__ unsigned short Ys[2][4096];

  const int z = blockIdx.z;
  const unsigned short* X = ws + (size_t)5 * SZT + (size_t)((z < 3) ? 0 : (z - 2)) * SZT;
  const unsigned short* W = ws + (size_t)8 * SZT + (size_t)z * WSZ;
  const float* bias = (z == 0) ? bq : (z == 1) ? bk : (z == 2) ? bv : (z == 3) ? bt : bs;
  unsigned short* out = ws + (size_t)((z < 2) ? z : (z == 2) ? 4 : (z == 3) ? 2 : 3) * SZT;

  const int tid   = threadIdx.x;
  const int lane  = tid & 63;
  const int wid   = tid >> 6;
  const int wm    = wid >> 1, wn = wid & 1;
  const int colid = lane & 15, quad = lane >> 4;
  const int m0 = blockIdx.y * 128, n0 = blockIdx.x * 128;

  auto stage = [&](int kt, int pb) {
#pragma unroll
    for (int i = 0; i < 2; ++i) {
      const int slot = i * 256 + tid;        // 0..511, 16B each
      const int row = slot >> 2, ch = slot & 3;
      gld16(X + (m0 + row) * HDIM + kt + ch * 8, &Xs[pb][slot * 8]);
      gld16(W + (n0 + row) * HDIM + kt + ch * 8, &Ys[pb][slot * 8]);
    }
  };

  fx4 acc[4][4];
#pragma unroll
  for (int i = 0; i < 4; ++i)
#pragma unroll
    for (int j = 0; j < 4; ++j) acc[i][j] = (fx4){0.f, 0.f, 0.f, 0.f};

  stage(0, 0);
  __syncthreads();

  for (int it = 0; it < 24; ++it) {
    const int pb = it & 1;
    if (it + 1 < 24) stage((it + 1) * 32, pb ^ 1);

    bf8 af[4], bfr[4];
#pragma unroll
    for (int i = 0; i < 4; ++i)
      af[i] = *(const bf8*)&Xs[pb][(wm * 64 + i * 16 + colid) * 32 + quad * 8];
#pragma unroll
    for (int j = 0; j < 4; ++j)
      bfr[j] = *(const bf8*)&Ys[pb][(wn * 64 + j * 16 + colid) * 32 + quad * 8];
#pragma unroll
    for (int i = 0; i < 4; ++i)
#pragma unroll
      for (int j = 0; j < 4; ++j)
        acc[i][j] = __builtin_amdgcn_mfma_f32_16x16x32_bf16(af[i], bfr[j], acc[i][j], 0, 0, 0);
    __syncthreads();
  }

  // Epilogue. C/D layout: col=lane&15, row=quad*4+reg.
  if (z != 2) {
#pragma unroll
    for (int i = 0; i < 4; ++i) {
      const int r0 = m0 + wm * 64 + i * 16 + quad * 4;
      const int bb = r0 >> 10, s0 = r0 & 1023;
#pragma unroll
      for (int j = 0; j < 4; ++j) {
        const int c = n0 + wn * 64 + j * 16 + colid;
        const int h = c >> 6, d = c & 63;
        const float bvl = bias[c];
        unsigned short* op = out + (((bb * NHEADS + h) * SEQ + s0) * DHEAD + d);
#pragma unroll
        for (int reg = 0; reg < 4; ++reg)
          op[reg * DHEAD] = f2bf(acc[i][j][reg] + bvl);
      }
    }
  } else {
    // V -> f16, transposed: Vt[(bh*64+d)*1024 + s], 4 consecutive s per 8B store.
#pragma unroll
    for (int i = 0; i < 4; ++i) {
      const int r0 = m0 + wm * 64 + i * 16 + quad * 4;
      const int bb = r0 >> 10, s0 = r0 & 1023;
#pragma unroll
      for (int j = 0; j < 4; ++j) {
        const int c = n0 + wn * 64 + j * 16 + colid;
        const int h = c >> 6, d = c & 63;
        const float bvl = bias[c];
        h4 pk;
#pragma unroll
        for (int reg = 0; reg < 4; ++reg)
          pk[reg] = (_Float16)(acc[i][j][reg] + bvl);
        *(h4*)(void*)(out + ((size_t)((bb * NHEADS + h) * DHEAD + d)) * SEQ + s0) = pk;
      }
    }
  }
}

// ---------------------------------------------------------------------------
// Flash attention. Round 13: r3 structure (proven 60.6us optimum of the
// ILP/TLP ridge: 4 waves x 32q, K/T/S/V in 64KB LDS dbuf, grid 384, ~120
// VGPR) + three intra-wave critical-path cuts that leave structure intact:
//  - T13 defer-max THR=8: skip O/l-rescale when __all(bm <= m+8) (~5%)
//  - T17 v_max3 tree for the 8-value tile max (depth 7 -> 3)
//  - T5 setprio(1) around QK and PV MFMA clusters (attn-proven +4-7%)
// Occupancy-raising restructures (r1/r4/r5/r6) all lost: per-wave efficiency
// drops faster than residency gains. Do not shrink q/wave below 32; do not
// cap VGPR below ~120.
// ---------------------------------------------------------------------------
__global__ __launch_bounds__(256, 2)
void attn_kernel(const unsigned short* __restrict__ ws,
                 const float* __restrict__ maskb,
                 float* __restrict__ outb)
{
  const unsigned short* Qb  = ws;
  const unsigned short* GT0 = ws + (size_t)1 * SZT;   // K
  const unsigned short* GT1 = ws + (size_t)2 * SZT;   // T
  const unsigned short* GT2 = ws + (size_t)3 * SZT;   // S
  const unsigned short* Vtu = ws + (size_t)4 * SZT;   // V f16 transposed, as ushort

  __shared__ unsigned short Ls[2][4][64][64];  // 64 KB: [buf][K,T,S,V][row][col]

  const int tid   = threadIdx.x;
  const int lane  = tid & 63;
  const int wid   = tid >> 6;          // 0..3
  const int colid = lane & 15, quad = lane >> 4;

  // XCD swizzle: 384 blocks; lin&7 = XCD; each XCD owns 6 bh entirely.
  const int lin = blockIdx.x;
  const int xcd = lin & 7;
  const int idx = lin >> 3;            // 0..47
  const int bh  = xcd * 6 + (idx % 6);
  const int qx  = idx / 6;             // 0..7
  const int b   = bh / NHEADS, h = bh % NHEADS;
  const int q0  = qx * 128 + wid * 32;
  const int base_h = bh * SEQ * DHEAD;

  // Query-side B-frags for 2 q-groups: lane holds B[k=quad*8+j][n=colid].
  bf8 bqf[2][2], btf[2][2], bsf[2][2];
  float rs[2];
#pragma unroll
  for (int g = 0; g < 2; ++g) {
    const int row = q0 + g * 16 + colid;
    const unsigned short* qp = Qb  + base_h + row * 64 + quad * 8;
    const unsigned short* tp = GT1 + base_h + row * 64 + quad * 8;
    const unsigned short* sp = GT2 + base_h + row * 64 + quad * 8;
    bqf[g][0] = *(const bf8*)qp;  bqf[g][1] = *(const bf8*)(qp + 32);
    btf[g][0] = *(const bf8*)tp;  btf[g][1] = *(const bf8*)(tp + 32);
    bsf[g][0] = *(const bf8*)sp;  bsf[g][1] = *(const bf8*)(sp + 32);
    float t2 = 0.f, s2 = 0.f;
#pragma unroll
    for (int fr = 0; fr < 2; ++fr)
#pragma unroll
      for (int j = 0; j < 8; ++j) {
        const float tv = bf2f((unsigned short)btf[g][fr][j]);
        const float sv2 = bf2f((unsigned short)bsf[g][fr][j]);
        t2 += tv * tv; s2 += sv2 * sv2;
      }
    t2 += __shfl_xor(t2, 16); t2 += __shfl_xor(t2, 32);
    s2 += __shfl_xor(s2, 16); s2 += __shfl_xor(s2, 32);
    rs[g] = 1.0f / ((sqrtf(t2) + EPSN) * (sqrtf(s2) + EPSN) * 8.0f);
  }

  // Cooperative staging of one 64-key tile: K,T,S [key][d] bf16 + V [d][key]
  // f16, 8 KB each. 2048 slots of 16B; slot s -> tensor s>>9, row (s>>3)&63,
  // col-slot s&7. Global source pre-swizzled so LDS holds slot^(row&7).
  auto stage = [&](int kb, int pb) {
#pragma unroll
    for (int i = 0; i < 8; ++i) {
      const int s  = i * 256 + tid;
      const int r  = (s >> 3) & 63;
      const int cs = ((s & 7) ^ (r & 7)) * 8;
      unsigned short* dst = &Ls[pb][0][0][0] + s * 8;
      if (i < 2)      gld16(GT0 + base_h + (kb + r) * 64 + cs, dst);
      else if (i < 4) gld16(GT1 + base_h + (kb + r) * 64 + cs, dst);
      else if (i < 6) gld16(GT2 + base_h + (kb + r) * 64 + cs, dst);
      else            gld16(Vtu + ((size_t)(bh * 64 + r)) * 1024 + kb + cs, dst);
    }
  };

  float m_[2], l_[2];
  fx4 o[2][4];
#pragma unroll
  for (int g = 0; g < 2; ++g) {
    m_[g] = -1.0e30f; l_[g] = 0.f;
#pragma unroll
    for (int fd = 0; fd < 4; ++fd) o[g][fd] = (fx4){0.f, 0.f, 0.f, 0.f};
  }
  const fx4 zero = (fx4){0.f, 0.f, 0.f, 0.f};

  stage(0, 0);
  __syncthreads();

#pragma unroll 1
  for (int t = 0; t < 16; ++t) {
    const int pb = t & 1;
    if (t + 1 < 16) stage((t + 1) * 64, pb ^ 1);
    const int kb = t * 64;

#pragma unroll
    for (int hh = 0; hh < 2; ++hh) {
      // ---- 32-key half: frags from LDS (swizzled reads) ----
      bf8 ak[2][2], at_[2][2], as_[2][2];
      h4 vv[2][4];
      fx4 mk[2];
#pragma unroll
      for (int ff = 0; ff < 2; ++ff) {
        const int f   = hh * 2 + ff;
        const int row = f * 16 + colid;
        const int sw  = row & 7;
#pragma unroll
        for (int fr = 0; fr < 2; ++fr) {
          const int co = ((quad + fr * 4) ^ sw) * 8;
          ak[ff][fr]  = *(const bf8*)&Ls[pb][0][row][co];
          at_[ff][fr] = *(const bf8*)&Ls[pb][1][row][co];
          as_[ff][fr] = *(const bf8*)&Ls[pb][2][row][co];
        }
#pragma unroll
        for (int fd = 0; fd < 4; ++fd) {
          const int vr = fd * 16 + colid;
          const int vo = (((f * 2 + (quad >> 1)) ^ (vr & 7)) * 8) + (quad & 1) * 4;
          vv[ff][fd] = *(const h4*)&Ls[pb][3][vr][vo];
        }
        mk[ff] = *(const fx4*)(maskb + b * SEQ + kb + f * 16 + quad * 4);
      }

      // ---- per q-group: scores^T, online softmax over 32 keys, PV ----
#pragma unroll
      for (int g = 0; g < 2; ++g) {
        float sv[2][4];
        __builtin_amdgcn_s_setprio(1);
#pragma unroll
        for (int ff = 0; ff < 2; ++ff) {
          fx4 ab = __builtin_amdgcn_mfma_f32_16x16x32_bf16(ak[ff][0], bqf[g][0], zero, 0, 0, 0);
          ab = __builtin_amdgcn_mfma_f32_16x16x32_bf16(ak[ff][1], bqf[g][1], ab, 0, 0, 0);
          fx4 tt = __builtin_amdgcn_mfma_f32_16x16x32_bf16(at_[ff][0], btf[g][0], zero, 0, 0, 0);
          tt = __builtin_amdgcn_mfma_f32_16x16x32_bf16(at_[ff][1], btf[g][1], tt, 0, 0, 0);
          fx4 ss = __builtin_amdgcn_mfma_f32_16x16x32_bf16(as_[ff][0], bsf[g][0], zero, 0, 0, 0);
          ss = __builtin_amdgcn_mfma_f32_16x16x32_bf16(as_[ff][1], bsf[g][1], ss, 0, 0, 0);
#pragma unroll
          for (int reg = 0; reg < 4; ++reg)
            sv[ff][reg] = (ab[reg] * tt[reg]) * ss[reg] * rs[g] + mk[ff][reg];
        }
        __builtin_amdgcn_s_setprio(0);

        // T17: max3 tree (compiler fuses fmaxf(fmaxf(a,b),c) -> v_max3_f32)
        const float m01 = fmaxf(fmaxf(sv[0][0], sv[0][1]), sv[0][2]);
        const float m02 = fmaxf(fmaxf(sv[0][3], sv[1][0]), sv[1][1]);
        const float m03 = fmaxf(fmaxf(sv[1][2], sv[1][3]), m01);
        float bm = fmaxf(m02, m03);
        bm = fmaxf(bm, __shfl_xor(bm, 16));
        bm = fmaxf(bm, __shfl_xor(bm, 32));

        // T13 defer-max: rescale only when tile max exceeds running max + 8.
        // p is then bounded by e^8 ~ 2981 (fits f16); first tile always
        // rescales (bm <= -1e30+8 is false).
        if (!__all(bm <= m_[g] + 8.0f)) {
          const float mn = fmaxf(m_[g], bm);
          const float alpha = __expf(m_[g] - mn);
          l_[g] *= alpha;
          m_[g] = mn;
          float ar[4];
#pragma unroll
          for (int reg = 0; reg < 4; ++reg) ar[reg] = __shfl(alpha, quad * 4 + reg);
#pragma unroll
          for (int fd = 0; fd < 4; ++fd)
#pragma unroll
            for (int reg = 0; reg < 4; ++reg) o[g][fd][reg] *= ar[reg];
        }

        const float mloc = m_[g];
        float rsum = 0.f;
        h4 pa[2];
#pragma unroll
        for (int ff = 0; ff < 2; ++ff)
#pragma unroll
          for (int reg = 0; reg < 4; ++reg) {
            const float p = __expf(sv[ff][reg] - mloc);
            rsum += p;
            pa[ff][reg] = (_Float16)p;
          }
        rsum += __shfl_xor(rsum, 16);
        rsum += __shfl_xor(rsum, 32);
        l_[g] += rsum;

        __builtin_amdgcn_s_setprio(1);
#pragma unroll
        for (int ff = 0; ff < 2; ++ff)
#pragma unroll
          for (int fd = 0; fd < 4; ++fd)
            o[g][fd] = __builtin_amdgcn_mfma_f32_16x16x16f16(pa[ff], vv[ff][fd], o[g][fd], 0, 0, 0);
        __builtin_amdgcn_s_setprio(0);
      }
    }
    __syncthreads();
  }

  // Epilogue per group: out[b, s, h*64+d] = O / l  (f32 out).
#pragma unroll
  for (int g = 0; g < 2; ++g) {
    const float linv = 1.0f / l_[g];
    float ir[4];
#pragma unroll
    for (int reg = 0; reg < 4; ++reg) ir[reg] = __shfl(linv, quad * 4 + reg);
#pragma unroll
    for (int reg = 0; reg < 4; ++reg) {
      const int s = q0 + g * 16 + quad * 4 + reg;
#pragma unroll
      for (int fd = 0; fd < 4; ++fd)
        outb[(size_t)(b * SEQ + s) * HDIM + h * DHEAD + fd * 16 + colid] = o[g][fd][reg] * ir[reg];
    }
  }
}

extern "C" void kernel_launch(void* const* d_in, const int* in_sizes, int n_in,
                              void* d_out, int out_size, void* d_ws, size_t ws_size,
                              hipStream_t stream)
{
  (void)in_sizes; (void)n_in; (void)out_size; (void)ws_size;
  const float* hs   = (const float*)d_in[0];
  const float* te   = (const float*)d_in[1];
  const float* se   = (const float*)d_in[2];
  const float* mask = (const float*)d_in[3];
  const float* Wq   = (const float*)d_in[4];
  const float* bq   = (const float*)d_in[5];
  const float* Wk   = (const float*)d_in[6];
  const float* bk   = (const float*)d_in[7];
  const float* Wv   = (const float*)d_in[8];
  const float* bv   = (const float*)d_in[9];
  const float* Wt   = (const float*)d_in[10];
  const float* bt   = (const float*)d_in[11];
  const float* Wsp  = (const float*)d_in[12];
  const float* bsp  = (const float*)d_in[13];
  float* out = (float*)d_out;
  unsigned short* ws = (unsigned short*)d_ws;

  // ws layout (ushort units): Qb@0 Kb@1SZ Tb@2SZ Sb@3SZ Vt(f16)@4SZ
  // convert-phase: hsb@5SZ teb@6SZ seb@7SZ W[5]@8SZ+z*WSZ (dead after proj)
  convert_kernel<<<dim3(1536, 8), 256, 0, stream>>>(hs, te, se, Wq, Wk, Wv, Wt, Wsp, ws);
  proj_kernel<<<dim3(6, 32, 5), 256, 0, stream>>>(ws, bq, bk, bv, bt, bsp);
  attn_kernel<<<dim3(384), 256, 0, stream>>>(ws, mask, out);
}

// Round 8
// 200.429 us; speedup vs baseline: 1.0712x; 1.0238x over previous
//
#include <hip/hip_runtime.h>

#define NHEADS 12
#define SEQ    1024
#define HDIM   768
#define DHEAD  64
#define BH_TOT 48
#define EPSN   1e-6f

typedef __attribute__((ext_vector_type(8))) short    bf8;  // 8 bf16 (4 VGPRs) MFMA A/B frag
typedef __attribute__((ext_vector_type(4))) float    fx4;  // MFMA C/D frag / float4
typedef __attribute__((ext_vector_type(4))) _Float16 h4;   // 4 f16 (2 VGPRs) 16x16x16 frag

#define SZT 3145728u   // 48*1024*64 elements (one head-split tensor)
#define WSZ 589824u    // 768*768 elements (one weight matrix)

__device__ __forceinline__ float bf2f(unsigned short h) {
  union { unsigned int u; float f; } v; v.u = ((unsigned int)h) << 16; return v.f;
}
__device__ __forceinline__ unsigned short f2bf(float f) {
  union { float f; unsigned int u; } v; v.f = f;
  unsigned int u = v.u;
  return (unsigned short)((u + 0x7FFFu + ((u >> 16) & 1u)) >> 16);
}

// async global->LDS, 16B per lane; LDS dest = wave-uniform base + lane*16.
typedef __attribute__((address_space(3))) unsigned int lds_u32;
typedef __attribute__((address_space(1))) const unsigned int glb_u32;
__device__ __forceinline__ void gld16(const unsigned short* g, unsigned short* l) {
  __builtin_amdgcn_global_load_lds((glb_u32*)g, (lds_u32*)l, 16, 0, 0);
}

// ---------------------------------------------------------------------------
// One-shot f32 -> bf16 conversion of X (hs,te,se) and W (q,k,v,t,s) into ws.
// Layout (ushort units): hsb@5SZ teb@6SZ seb@7SZ  W[z]@8SZ + z*WSZ
// ---------------------------------------------------------------------------
__global__ void convert_kernel(const float* __restrict__ hs, const float* __restrict__ te,
                               const float* __restrict__ se,
                               const float* __restrict__ Wq, const float* __restrict__ Wk,
                               const float* __restrict__ Wv, const float* __restrict__ Wt,
                               const float* __restrict__ Ws2,
                               unsigned short* __restrict__ ws)
{
  const int z = blockIdx.y;
  const float* src;
  unsigned short* dst;
  int n;
  if (z < 3) {
    src = (z == 0) ? hs : (z == 1) ? te : se;
    dst = ws + (size_t)(5 + z) * SZT;
    n = 3145728;
  } else {
    src = (z == 3) ? Wq : (z == 4) ? Wk : (z == 5) ? Wv : (z == 6) ? Wt : Ws2;
    dst = ws + (size_t)8 * SZT + (size_t)(z - 3) * WSZ;
    n = 589824;
  }
  const int base = (blockIdx.x * 256 + threadIdx.x) * 8;
  if (base >= n) return;
  const fx4 a = *(const fx4*)(src + base);
  const fx4 b = *(const fx4*)(src + base + 4);
  bf8 o;
#pragma unroll
  for (int j = 0; j < 4; ++j) { o[j] = (short)f2bf(a[j]); o[4 + j] = (short)f2bf(b[j]); }
  *(bf8*)(dst + base) = o;
}

// ---------------------------------------------------------------------------
// Projection GEMM (bf16 in): out = X[4096,768] @ W[768,768]^T + b, head-split.
// Round 14: XCD-aware block remap (T1). Old (x,y,z) grid scattered the 6
// x-blocks sharing an X panel (196KB) across 6 XCDs, and the 32 y-blocks
// sharing a W panel across all XCDs -> est. ~380 MB HBM refetch (~60us,
// roughly proj's whole runtime). New 1-D grid 960 (960%8==0, bijective):
// xcd = lin&7 owns y-tiles xcd*4..xcd*4+3 for ALL x and z, so same-XCD
// blocks share X panels (784KB, L2-resident) + W panels. Pure index
// permutation: zero numerics/schedule risk.
// z: 0=Q 1=K 2=V(f16, transposed Vt[bh*64+d][1024]) 3=T 4=S
// ---------------------------------------------------------------------------
__global__ __launch_bounds__(256, 3)
void proj_kernel(unsigned short* __restrict__ ws,
                 const float* __restrict__ bq, const float* __restrict__ bk,
                 const float* __restrict__ bv, const float* __restrict__ bt,
                 const float* __restrict__ bs)
{
  __shared__ unsigned short Xs[2][4096];
  __shared__ unsigned short Ys[2][4096];

  // Decode XCD-grouped tile assignment from 1-D block id.
  const int lin = blockIdx.x;          // 0..959
  const int xcd = lin & 7;
  const int idx = lin >> 3;            // 0..119
  const int xt  = idx % 6;             // N-tile
  const int t2  = idx / 6;             // 0..19
  const int yl  = t2 % 4;
  const int z   = t2 / 4;              // 0..4
  const int yt  = xcd * 4 + yl;        // M-tile, grouped per XCD

  const unsigned short* X = ws + (size_t)5 * SZT + (size_t)((z < 3) ? 0 : (z - 2)) * SZT;
  const unsigned short* W = ws + (size_t)8 * SZT + (size_t)z * WSZ;
  const float* bias = (z == 0) ? bq : (z == 1) ? bk : (z == 2) ? bv : (z == 3) ? bt : bs;
  unsigned short* out = ws + (size_t)((z < 2) ? z : (z == 2) ? 4 : (z == 3) ? 2 : 3) * SZT;

  const int tid   = threadIdx.x;
  const int lane  = tid & 63;
  const int wid   = tid >> 6;
  const int wm    = wid >> 1, wn = wid & 1;
  const int colid = lane & 15, quad = lane >> 4;
  const int m0 = yt * 128, n0 = xt * 128;

  auto stage = [&](int kt, int pb) {
#pragma unroll
    for (int i = 0; i < 2; ++i) {
      const int slot = i * 256 + tid;        // 0..511, 16B each
      const int row = slot >> 2, ch = slot & 3;
      gld16(X + (m0 + row) * HDIM + kt + ch * 8, &Xs[pb][slot * 8]);
      gld16(W + (n0 + row) * HDIM + kt + ch * 8, &Ys[pb][slot * 8]);
    }
  };

  fx4 acc[4][4];
#pragma unroll
  for (int i = 0; i < 4; ++i)
#pragma unroll
    for (int j = 0; j < 4; ++j) acc[i][j] = (fx4){0.f, 0.f, 0.f, 0.f};

  stage(0, 0);
  __syncthreads();

  for (int it = 0; it < 24; ++it) {
    const int pb = it & 1;
    if (it + 1 < 24) stage((it + 1) * 32, pb ^ 1);

    bf8 af[4], bfr[4];
#pragma unroll
    for (int i = 0; i < 4; ++i)
      af[i] = *(const bf8*)&Xs[pb][(wm * 64 + i * 16 + colid) * 32 + quad * 8];
#pragma unroll
    for (int j = 0; j < 4; ++j)
      bfr[j] = *(const bf8*)&Ys[pb][(wn * 64 + j * 16 + colid) * 32 + quad * 8];
#pragma unroll
    for (int i = 0; i < 4; ++i)
#pragma unroll
      for (int j = 0; j < 4; ++j)
        acc[i][j] = __builtin_amdgcn_mfma_f32_16x16x32_bf16(af[i], bfr[j], acc[i][j], 0, 0, 0);
    __syncthreads();
  }

  // Epilogue. C/D layout: col=lane&15, row=quad*4+reg.
  if (z != 2) {
#pragma unroll
    for (int i = 0; i < 4; ++i) {
      const int r0 = m0 + wm * 64 + i * 16 + quad * 4;
      const int bb = r0 >> 10, s0 = r0 & 1023;
#pragma unroll
      for (int j = 0; j < 4; ++j) {
        const int c = n0 + wn * 64 + j * 16 + colid;
        const int h = c >> 6, d = c & 63;
        const float bvl = bias[c];
        unsigned short* op = out + (((bb * NHEADS + h) * SEQ + s0) * DHEAD + d);
#pragma unroll
        for (int reg = 0; reg < 4; ++reg)
          op[reg * DHEAD] = f2bf(acc[i][j][reg] + bvl);
      }
    }
  } else {
    // V -> f16, transposed: Vt[(bh*64+d)*1024 + s], 4 consecutive s per 8B store.
#pragma unroll
    for (int i = 0; i < 4; ++i) {
      const int r0 = m0 + wm * 64 + i * 16 + quad * 4;
      const int bb = r0 >> 10, s0 = r0 & 1023;
#pragma unroll
      for (int j = 0; j < 4; ++j) {
        const int c = n0 + wn * 64 + j * 16 + colid;
        const int h = c >> 6, d = c & 63;
        const float bvl = bias[c];
        h4 pk;
#pragma unroll
        for (int reg = 0; reg < 4; ++reg)
          pk[reg] = (_Float16)(acc[i][j][reg] + bvl);
        *(h4*)(void*)(out + ((size_t)((bb * NHEADS + h) * DHEAD + d)) * SEQ + s0) = pk;
      }
    }
  }
}

// ---------------------------------------------------------------------------
// Flash attention. Round 14: byte-exact revert to the round-3 optimum
// (60.6us). r7's bundled tweaks (setprio fences + defer-max branch + max3)
// cost 21%: setprio intrinsics fence the scheduler, killing MFMA/VALU
// overlap in this 1-wave/SIMD structure (m190/rule-19), and the defer-max
// branch pins o/l live ranges. LAWS for this kernel: (1) never shrink
// q/wave below 32 (r1/r4); (2) don't buy occupancy with VGPR caps or AI
// (r1/r4/r5/r6); (3) don't fence the inner loop with intrinsics (r7).
// Structure: 4 waves x 32 q, K/T/S/V staged in 64KB dbuf LDS via gld16 with
// 16B-slot XOR swizzle (pre-swizzled global source, linear LDS dest), grid
// 384 XCD-grouped, per-lane softmax over transposed scores, f16 PV.
// ---------------------------------------------------------------------------
__global__ __launch_bounds__(256, 2)
void attn_kernel(const unsigned short* __restrict__ ws,
                 const float* __restrict__ maskb,
                 float* __restrict__ outb)
{
  const unsigned short* Qb  = ws;
  const unsigned short* GT0 = ws + (size_t)1 * SZT;   // K
  const unsigned short* GT1 = ws + (size_t)2 * SZT;   // T
  const unsigned short* GT2 = ws + (size_t)3 * SZT;   // S
  const unsigned short* Vtu = ws + (size_t)4 * SZT;   // V f16 transposed, as ushort

  __shared__ unsigned short Ls[2][4][64][64];  // 64 KB: [buf][K,T,S,V][row][col]

  const int tid   = threadIdx.x;
  const int lane  = tid & 63;
  const int wid   = tid >> 6;          // 0..3
  const int colid = lane & 15, quad = lane >> 4;

  // XCD swizzle: 384 blocks; lin&7 = XCD; each XCD owns 6 bh entirely.
  const int lin = blockIdx.x;
  const int xcd = lin & 7;
  const int idx = lin >> 3;            // 0..47
  const int bh  = xcd * 6 + (idx % 6);
  const int qx  = idx / 6;             // 0..7
  const int b   = bh / NHEADS, h = bh % NHEADS;
  const int q0  = qx * 128 + wid * 32;
  const int base_h = bh * SEQ * DHEAD;

  // Query-side B-frags for 2 q-groups: lane holds B[k=quad*8+j][n=colid].
  bf8 bqf[2][2], btf[2][2], bsf[2][2];
  float rs[2];
#pragma unroll
  for (int g = 0; g < 2; ++g) {
    const int row = q0 + g * 16 + colid;
    const unsigned short* qp = Qb  + base_h + row * 64 + quad * 8;
    const unsigned short* tp = GT1 + base_h + row * 64 + quad * 8;
    const unsigned short* sp = GT2 + base_h + row * 64 + quad * 8;
    bqf[g][0] = *(const bf8*)qp;  bqf[g][1] = *(const bf8*)(qp + 32);
    btf[g][0] = *(const bf8*)tp;  btf[g][1] = *(const bf8*)(tp + 32);
    bsf[g][0] = *(const bf8*)sp;  bsf[g][1] = *(const bf8*)(sp + 32);
    float t2 = 0.f, s2 = 0.f;
#pragma unroll
    for (int fr = 0; fr < 2; ++fr)
#pragma unroll
      for (int j = 0; j < 8; ++j) {
        const float tv = bf2f((unsigned short)btf[g][fr][j]);
        const float sv2 = bf2f((unsigned short)bsf[g][fr][j]);
        t2 += tv * tv; s2 += sv2 * sv2;
      }
    t2 += __shfl_xor(t2, 16); t2 += __shfl_xor(t2, 32);
    s2 += __shfl_xor(s2, 16); s2 += __shfl_xor(s2, 32);
    rs[g] = 1.0f / ((sqrtf(t2) + EPSN) * (sqrtf(s2) + EPSN) * 8.0f);
  }

  // Cooperative staging of one 64-key tile: K,T,S [key][d] bf16 + V [d][key]
  // f16, 8 KB each. 2048 slots of 16B; slot s -> tensor s>>9, row (s>>3)&63,
  // col-slot s&7. Global source pre-swizzled so LDS holds slot^(row&7).
  auto stage = [&](int kb, int pb) {
#pragma unroll
    for (int i = 0; i < 8; ++i) {
      const int s  = i * 256 + tid;
      const int r  = (s >> 3) & 63;
      const int cs = ((s & 7) ^ (r & 7)) * 8;
      unsigned short* dst = &Ls[pb][0][0][0] + s * 8;
      if (i < 2)      gld16(GT0 + base_h + (kb + r) * 64 + cs, dst);
      else if (i < 4) gld16(GT1 + base_h + (kb + r) * 64 + cs, dst);
      else if (i < 6) gld16(GT2 + base_h + (kb + r) * 64 + cs, dst);
      else            gld16(Vtu + ((size_t)(bh * 64 + r)) * 1024 + kb + cs, dst);
    }
  };

  float m_[2], l_[2];
  fx4 o[2][4];
#pragma unroll
  for (int g = 0; g < 2; ++g) {
    m_[g] = -1.0e30f; l_[g] = 0.f;
#pragma unroll
    for (int fd = 0; fd < 4; ++fd) o[g][fd] = (fx4){0.f, 0.f, 0.f, 0.f};
  }
  const fx4 zero = (fx4){0.f, 0.f, 0.f, 0.f};

  stage(0, 0);
  __syncthreads();

#pragma unroll 1
  for (int t = 0; t < 16; ++t) {
    const int pb = t & 1;
    if (t + 1 < 16) stage((t + 1) * 64, pb ^ 1);
    const int kb = t * 64;

#pragma unroll
    for (int hh = 0; hh < 2; ++hh) {
      // ---- 32-key half: frags from LDS (swizzled reads) ----
      bf8 ak[2][2], at_[2][2], as_[2][2];
      h4 vv[2][4];
      fx4 mk[2];
#pragma unroll
      for (int ff = 0; ff < 2; ++ff) {
        const int f   = hh * 2 + ff;
        const int row = f * 16 + colid;
        const int sw  = row & 7;
#pragma unroll
        for (int fr = 0; fr < 2; ++fr) {
          const int co = ((quad + fr * 4) ^ sw) * 8;
          ak[ff][fr]  = *(const bf8*)&Ls[pb][0][row][co];
          at_[ff][fr] = *(const bf8*)&Ls[pb][1][row][co];
          as_[ff][fr] = *(const bf8*)&Ls[pb][2][row][co];
        }
#pragma unroll
        for (int fd = 0; fd < 4; ++fd) {
          const int vr = fd * 16 + colid;
          const int vo = (((f * 2 + (quad >> 1)) ^ (vr & 7)) * 8) + (quad & 1) * 4;
          vv[ff][fd] = *(const h4*)&Ls[pb][3][vr][vo];
        }
        mk[ff] = *(const fx4*)(maskb + b * SEQ + kb + f * 16 + quad * 4);
      }

      // ---- per q-group: scores^T, online softmax over 32 keys, PV ----
#pragma unroll
      for (int g = 0; g < 2; ++g) {
        float sv[2][4];
#pragma unroll
        for (int ff = 0; ff < 2; ++ff) {
          fx4 ab = __builtin_amdgcn_mfma_f32_16x16x32_bf16(ak[ff][0], bqf[g][0], zero, 0, 0, 0);
          ab = __builtin_amdgcn_mfma_f32_16x16x32_bf16(ak[ff][1], bqf[g][1], ab, 0, 0, 0);
          fx4 tt = __builtin_amdgcn_mfma_f32_16x16x32_bf16(at_[ff][0], btf[g][0], zero, 0, 0, 0);
          tt = __builtin_amdgcn_mfma_f32_16x16x32_bf16(at_[ff][1], btf[g][1], tt, 0, 0, 0);
          fx4 ss = __builtin_amdgcn_mfma_f32_16x16x32_bf16(as_[ff][0], bsf[g][0], zero, 0, 0, 0);
          ss = __builtin_amdgcn_mfma_f32_16x16x32_bf16(as_[ff][1], bsf[g][1], ss, 0, 0, 0);
#pragma unroll
          for (int reg = 0; reg < 4; ++reg)
            sv[ff][reg] = (ab[reg] * tt[reg]) * ss[reg] * rs[g] + mk[ff][reg];
        }

        float bm = sv[0][0];
#pragma unroll
        for (int ff = 0; ff < 2; ++ff)
#pragma unroll
          for (int reg = 0; reg < 4; ++reg) bm = fmaxf(bm, sv[ff][reg]);
        bm = fmaxf(bm, __shfl_xor(bm, 16));
        bm = fmaxf(bm, __shfl_xor(bm, 32));
        const float mn = fmaxf(m_[g], bm);
        const float alpha = __expf(m_[g] - mn);
        float rsum = 0.f;
        h4 pa[2];
#pragma unroll
        for (int ff = 0; ff < 2; ++ff)
#pragma unroll
          for (int reg = 0; reg < 4; ++reg) {
            const float p = __expf(sv[ff][reg] - mn);
            rsum += p;
            pa[ff][reg] = (_Float16)p;
          }
        rsum += __shfl_xor(rsum, 16);
        rsum += __shfl_xor(rsum, 32);
        l_[g] = l_[g] * alpha + rsum;
        m_[g] = mn;

        float ar[4];
#pragma unroll
        for (int reg = 0; reg < 4; ++reg) ar[reg] = __shfl(alpha, quad * 4 + reg);
#pragma unroll
        for (int fd = 0; fd < 4; ++fd)
#pragma unroll
          for (int reg = 0; reg < 4; ++reg) o[g][fd][reg] *= ar[reg];

#pragma unroll
        for (int ff = 0; ff < 2; ++ff)
#pragma unroll
          for (int fd = 0; fd < 4; ++fd)
            o[g][fd] = __builtin_amdgcn_mfma_f32_16x16x16f16(pa[ff], vv[ff][fd], o[g][fd], 0, 0, 0);
      }
    }
    __syncthreads();
  }

  // Epilogue per group: out[b, s, h*64+d] = O / l  (f32 out).
#pragma unroll
  for (int g = 0; g < 2; ++g) {
    const float linv = 1.0f / l_[g];
    float ir[4];
#pragma unroll
    for (int reg = 0; reg < 4; ++reg) ir[reg] = __shfl(linv, quad * 4 + reg);
#pragma unroll
    for (int reg = 0; reg < 4; ++reg) {
      const int s = q0 + g * 16 + quad * 4 + reg;
#pragma unroll
      for (int fd = 0; fd < 4; ++fd)
        outb[(size_t)(b * SEQ + s) * HDIM + h * DHEAD + fd * 16 + colid] = o[g][fd][reg] * ir[reg];
    }
  }
}

extern "C" void kernel_launch(void* const* d_in, const int* in_sizes, int n_in,
                              void* d_out, int out_size, void* d_ws, size_t ws_size,
                              hipStream_t stream)
{
  (void)in_sizes; (void)n_in; (void)out_size; (void)ws_size;
  const float* hs   = (const float*)d_in[0];
  const float* te   = (const float*)d_in[1];
  const float* se   = (const float*)d_in[2];
  const float* mask = (const float*)d_in[3];
  const float* Wq   = (const float*)d_in[4];
  const float* bq   = (const float*)d_in[5];
  const float* Wk   = (const float*)d_in[6];
  const float* bk   = (const float*)d_in[7];
  const float* Wv   = (const float*)d_in[8];
  const float* bv   = (const float*)d_in[9];
  const float* Wt   = (const float*)d_in[10];
  const float* bt   = (const float*)d_in[11];
  const float* Wsp  = (const float*)d_in[12];
  const float* bsp  = (const float*)d_in[13];
  float* out = (float*)d_out;
  unsigned short* ws = (unsigned short*)d_ws;

  // ws layout (ushort units): Qb@0 Kb@1SZ Tb@2SZ Sb@3SZ Vt(f16)@4SZ
  // convert-phase: hsb@5SZ teb@6SZ seb@7SZ W[5]@8SZ+z*WSZ (dead after proj)
  convert_kernel<<<dim3(1536, 8), 256, 0, stream>>>(hs, te, se, Wq, Wk, Wv, Wt, Wsp, ws);
  proj_kernel<<<dim3(960), 256, 0, stream>>>(ws, bq, bk, bv, bt, bsp);
  attn_kernel<<<dim3(384), 256, 0, stream>>>(ws, mask, out);
}

// Round 9
// 194.053 us; speedup vs baseline: 1.1064x; 1.0329x over previous
//
#include <hip/hip_runtime.h>

#define NHEADS 12
#define SEQ    1024
#define HDIM   768
#define DHEAD  64
#define BH_TOT 48
#define EPSN   1e-6f

typedef __attribute__((ext_vector_type(8))) short    bf8;  // 8 bf16 (4 VGPRs) MFMA A/B frag
typedef __attribute__((ext_vector_type(4))) float    fx4;  // MFMA C/D frag / float4
typedef __attribute__((ext_vector_type(4))) _Float16 h4;   // 4 f16 (2 VGPRs) 16x16x16 frag

#define SZT 3145728u   // 48*1024*64 elements (one head-split tensor)
#define WSZ 589824u    // 768*768 elements (one weight matrix)

__device__ __forceinline__ float bf2f(unsigned short h) {
  union { unsigned int u; float f; } v; v.u = ((unsigned int)h) << 16; return v.f;
}
__device__ __forceinline__ unsigned short f2bf(float f) {
  union { float f; unsigned int u; } v; v.f = f;
  unsigned int u = v.u;
  return (unsigned short)((u + 0x7FFFu + ((u >> 16) & 1u)) >> 16);
}

// async global->LDS, 16B per lane; LDS dest = wave-uniform base + lane*16.
typedef __attribute__((address_space(3))) unsigned int lds_u32;
typedef __attribute__((address_space(1))) const unsigned int glb_u32;
__device__ __forceinline__ void gld16(const unsigned short* g, unsigned short* l) {
  __builtin_amdgcn_global_load_lds((glb_u32*)g, (lds_u32*)l, 16, 0, 0);
}

// ---------------------------------------------------------------------------
// One-shot f32 -> bf16 conversion of X (hs,te,se) and W (q,k,v,t,s) into ws.
// Layout (ushort units): hsb@5SZ teb@6SZ seb@7SZ  W[z]@8SZ + z*WSZ
// ---------------------------------------------------------------------------
__global__ void convert_kernel(const float* __restrict__ hs, const float* __restrict__ te,
                               const float* __restrict__ se,
                               const float* __restrict__ Wq, const float* __restrict__ Wk,
                               const float* __restrict__ Wv, const float* __restrict__ Wt,
                               const float* __restrict__ Ws2,
                               unsigned short* __restrict__ ws)
{
  const int z = blockIdx.y;
  const float* src;
  unsigned short* dst;
  int n;
  if (z < 3) {
    src = (z == 0) ? hs : (z == 1) ? te : se;
    dst = ws + (size_t)(5 + z) * SZT;
    n = 3145728;
  } else {
    src = (z == 3) ? Wq : (z == 4) ? Wk : (z == 5) ? Wv : (z == 6) ? Wt : Ws2;
    dst = ws + (size_t)8 * SZT + (size_t)(z - 3) * WSZ;
    n = 589824;
  }
  const int base = (blockIdx.x * 256 + threadIdx.x) * 8;
  if (base >= n) return;
  const fx4 a = *(const fx4*)(src + base);
  const fx4 b = *(const fx4*)(src + base + 4);
  bf8 o;
#pragma unroll
  for (int j = 0; j < 4; ++j) { o[j] = (short)f2bf(a[j]); o[4 + j] = (short)f2bf(b[j]); }
  *(bf8*)(dst + base) = o;
}

// ---------------------------------------------------------------------------
// Projection GEMM (bf16 in): out = X[4096,768] @ W[768,768]^T + b, head-split.
// XCD-aware 1-D grid 960 (r8, kept: small real win). xcd = lin&7 owns
// y-tiles xcd*4..xcd*4+3 for ALL x and z -> same-XCD blocks share X panels
// (784KB, L2-resident) + W panels.
// z: 0=Q 1=K 2=V(f16, transposed Vt[bh*64+d][1024]) 3=T 4=S
// ---------------------------------------------------------------------------
__global__ __launch_bounds__(256, 3)
void proj_kernel(unsigned short* __restrict__ ws,
                 const float* __restrict__ bq, const float* __restrict__ bk,
                 const float* __restrict__ bv, const float* __restrict__ bt,
                 const float* __restrict__ bs)
{
  __shared__ unsigned short Xs[2][4096];
  __shared__ unsigned short Ys[2][4096];

  // Decode XCD-grouped tile assignment from 1-D block id.
  const int lin = blockIdx.x;          // 0..959
  const int xcd = lin & 7;
  const int idx = lin >> 3;            // 0..119
  const int xt  = idx % 6;             // N-tile
  const int t2  = idx / 6;             // 0..19
  const int yl  = t2 % 4;
  const int z   = t2 / 4;              // 0..4
  const int yt  = xcd * 4 + yl;        // M-tile, grouped per XCD

  const unsigned short* X = ws + (size_t)5 * SZT + (size_t)((z < 3) ? 0 : (z - 2)) * SZT;
  const unsigned short* W = ws + (size_t)8 * SZT + (size_t)z * WSZ;
  const float* bias = (z == 0) ? bq : (z == 1) ? bk : (z == 2) ? bv : (z == 3) ? bt : bs;
  unsigned short* out = ws + (size_t)((z < 2) ? z : (z == 2) ? 4 : (z == 3) ? 2 : 3) * SZT;

  const int tid   = threadIdx.x;
  const int lane  = tid & 63;
  const int wid   = tid >> 6;
  const int wm    = wid >> 1, wn = wid & 1;
  const int colid = lane & 15, quad = lane >> 4;
  const int m0 = yt * 128, n0 = xt * 128;

  auto stage = [&](int kt, int pb) {
#pragma unroll
    for (int i = 0; i < 2; ++i) {
      const int slot = i * 256 + tid;        // 0..511, 16B each
      const int row = slot >> 2, ch = slot & 3;
      gld16(X + (m0 + row) * HDIM + kt + ch * 8, &Xs[pb][slot * 8]);
      gld16(W + (n0 + row) * HDIM + kt + ch * 8, &Ys[pb][slot * 8]);
    }
  };

  fx4 acc[4][4];
#pragma unroll
  for (int i = 0; i < 4; ++i)
#pragma unroll
    for (int j = 0; j < 4; ++j) acc[i][j] = (fx4){0.f, 0.f, 0.f, 0.f};

  stage(0, 0);
  __syncthreads();

  for (int it = 0; it < 24; ++it) {
    const int pb = it & 1;
    if (it + 1 < 24) stage((it + 1) * 32, pb ^ 1);

    bf8 af[4], bfr[4];
#pragma unroll
    for (int i = 0; i < 4; ++i)
      af[i] = *(const bf8*)&Xs[pb][(wm * 64 + i * 16 + colid) * 32 + quad * 8];
#pragma unroll
    for (int j = 0; j < 4; ++j)
      bfr[j] = *(const bf8*)&Ys[pb][(wn * 64 + j * 16 + colid) * 32 + quad * 8];
#pragma unroll
    for (int i = 0; i < 4; ++i)
#pragma unroll
      for (int j = 0; j < 4; ++j)
        acc[i][j] = __builtin_amdgcn_mfma_f32_16x16x32_bf16(af[i], bfr[j], acc[i][j], 0, 0, 0);
    __syncthreads();
  }

  // Epilogue. C/D layout: col=lane&15, row=quad*4+reg.
  if (z != 2) {
#pragma unroll
    for (int i = 0; i < 4; ++i) {
      const int r0 = m0 + wm * 64 + i * 16 + quad * 4;
      const int bb = r0 >> 10, s0 = r0 & 1023;
#pragma unroll
      for (int j = 0; j < 4; ++j) {
        const int c = n0 + wn * 64 + j * 16 + colid;
        const int h = c >> 6, d = c & 63;
        const float bvl = bias[c];
        unsigned short* op = out + (((bb * NHEADS + h) * SEQ + s0) * DHEAD + d);
#pragma unroll
        for (int reg = 0; reg < 4; ++reg)
          op[reg * DHEAD] = f2bf(acc[i][j][reg] + bvl);
      }
    }
  } else {
    // V -> f16, transposed: Vt[(bh*64+d)*1024 + s], 4 consecutive s per 8B store.
#pragma unroll
    for (int i = 0; i < 4; ++i) {
      const int r0 = m0 + wm * 64 + i * 16 + quad * 4;
      const int bb = r0 >> 10, s0 = r0 & 1023;
#pragma unroll
      for (int j = 0; j < 4; ++j) {
        const int c = n0 + wn * 64 + j * 16 + colid;
        const int h = c >> 6, d = c & 63;
        const float bvl = bias[c];
        h4 pk;
#pragma unroll
        for (int reg = 0; reg < 4; ++reg)
          pk[reg] = (_Float16)(acc[i][j][reg] + bvl);
        *(h4*)(void*)(out + ((size_t)((bb * NHEADS + h) * DHEAD + d)) * SEQ + s0) = pk;
      }
    }
  }
}

// ---------------------------------------------------------------------------
// Flash attention. Round 15: r3 structure + ONE change: T13 defer-max.
// r3/r8 baseline 60.6-62.1us is VALU-bound (VALUBusy 32 > MfmaUtil 20; per
// unit ~130 VALU cyc vs ~60 MFMA cyc). The unconditional online-softmax
// rescale (16 v_mul o-scale + 4 bpermute + exp + l-scale per unit x 64) is
// the largest removable VALU block: skip it when __all(bm <= m+8) -- true
// ~63/64 tiles for these norm-scaled scores. p <= e^8 fits f16; wave-uniform
// branch (no divergence); r7's absmax was bit-identical, confirming safety.
// (r7's regression is attributed to the bundled setprio fences; this round
// isolates defer-max per the one-change rule.)
// LAWS: (1) q/wave >= 32; (2) don't buy occupancy with VGPR caps or AI;
// (3) no scheduler-fencing intrinsics in the inner loop.
// ---------------------------------------------------------------------------
__global__ __launch_bounds__(256, 2)
void attn_kernel(const unsigned short* __restrict__ ws,
                 const float* __restrict__ maskb,
                 float* __restrict__ outb)
{
  const unsigned short* Qb  = ws;
  const unsigned short* GT0 = ws + (size_t)1 * SZT;   // K
  const unsigned short* GT1 = ws + (size_t)2 * SZT;   // T
  const unsigned short* GT2 = ws + (size_t)3 * SZT;   // S
  const unsigned short* Vtu = ws + (size_t)4 * SZT;   // V f16 transposed, as ushort

  __shared__ unsigned short Ls[2][4][64][64];  // 64 KB: [buf][K,T,S,V][row][col]

  const int tid   = threadIdx.x;
  const int lane  = tid & 63;
  const int wid   = tid >> 6;          // 0..3
  const int colid = lane & 15, quad = lane >> 4;

  // XCD swizzle: 384 blocks; lin&7 = XCD; each XCD owns 6 bh entirely.
  const int lin = blockIdx.x;
  const int xcd = lin & 7;
  const int idx = lin >> 3;            // 0..47
  const int bh  = xcd * 6 + (idx % 6);
  const int qx  = idx / 6;             // 0..7
  const int b   = bh / NHEADS, h = bh % NHEADS;
  const int q0  = qx * 128 + wid * 32;
  const int base_h = bh * SEQ * DHEAD;

  // Query-side B-frags for 2 q-groups: lane holds B[k=quad*8+j][n=colid].
  bf8 bqf[2][2], btf[2][2], bsf[2][2];
  float rs[2];
#pragma unroll
  for (int g = 0; g < 2; ++g) {
    const int row = q0 + g * 16 + colid;
    const unsigned short* qp = Qb  + base_h + row * 64 + quad * 8;
    const unsigned short* tp = GT1 + base_h + row * 64 + quad * 8;
    const unsigned short* sp = GT2 + base_h + row * 64 + quad * 8;
    bqf[g][0] = *(const bf8*)qp;  bqf[g][1] = *(const bf8*)(qp + 32);
    btf[g][0] = *(const bf8*)tp;  btf[g][1] = *(const bf8*)(tp + 32);
    bsf[g][0] = *(const bf8*)sp;  bsf[g][1] = *(const bf8*)(sp + 32);
    float t2 = 0.f, s2 = 0.f;
#pragma unroll
    for (int fr = 0; fr < 2; ++fr)
#pragma unroll
      for (int j = 0; j < 8; ++j) {
        const float tv = bf2f((unsigned short)btf[g][fr][j]);
        const float sv2 = bf2f((unsigned short)bsf[g][fr][j]);
        t2 += tv * tv; s2 += sv2 * sv2;
      }
    t2 += __shfl_xor(t2, 16); t2 += __shfl_xor(t2, 32);
    s2 += __shfl_xor(s2, 16); s2 += __shfl_xor(s2, 32);
    rs[g] = 1.0f / ((sqrtf(t2) + EPSN) * (sqrtf(s2) + EPSN) * 8.0f);
  }

  // Cooperative staging of one 64-key tile: K,T,S [key][d] bf16 + V [d][key]
  // f16, 8 KB each. 2048 slots of 16B; slot s -> tensor s>>9, row (s>>3)&63,
  // col-slot s&7. Global source pre-swizzled so LDS holds slot^(row&7).
  auto stage = [&](int kb, int pb) {
#pragma unroll
    for (int i = 0; i < 8; ++i) {
      const int s  = i * 256 + tid;
      const int r  = (s >> 3) & 63;
      const int cs = ((s & 7) ^ (r & 7)) * 8;
      unsigned short* dst = &Ls[pb][0][0][0] + s * 8;
      if (i < 2)      gld16(GT0 + base_h + (kb + r) * 64 + cs, dst);
      else if (i < 4) gld16(GT1 + base_h + (kb + r) * 64 + cs, dst);
      else if (i < 6) gld16(GT2 + base_h + (kb + r) * 64 + cs, dst);
      else            gld16(Vtu + ((size_t)(bh * 64 + r)) * 1024 + kb + cs, dst);
    }
  };

  float m_[2], l_[2];
  fx4 o[2][4];
#pragma unroll
  for (int g = 0; g < 2; ++g) {
    m_[g] = -1.0e30f; l_[g] = 0.f;
#pragma unroll
    for (int fd = 0; fd < 4; ++fd) o[g][fd] = (fx4){0.f, 0.f, 0.f, 0.f};
  }
  const fx4 zero = (fx4){0.f, 0.f, 0.f, 0.f};

  stage(0, 0);
  __syncthreads();

#pragma unroll 1
  for (int t = 0; t < 16; ++t) {
    const int pb = t & 1;
    if (t + 1 < 16) stage((t + 1) * 64, pb ^ 1);
    const int kb = t * 64;

#pragma unroll
    for (int hh = 0; hh < 2; ++hh) {
      // ---- 32-key half: frags from LDS (swizzled reads) ----
      bf8 ak[2][2], at_[2][2], as_[2][2];
      h4 vv[2][4];
      fx4 mk[2];
#pragma unroll
      for (int ff = 0; ff < 2; ++ff) {
        const int f   = hh * 2 + ff;
        const int row = f * 16 + colid;
        const int sw  = row & 7;
#pragma unroll
        for (int fr = 0; fr < 2; ++fr) {
          const int co = ((quad + fr * 4) ^ sw) * 8;
          ak[ff][fr]  = *(const bf8*)&Ls[pb][0][row][co];
          at_[ff][fr] = *(const bf8*)&Ls[pb][1][row][co];
          as_[ff][fr] = *(const bf8*)&Ls[pb][2][row][co];
        }
#pragma unroll
        for (int fd = 0; fd < 4; ++fd) {
          const int vr = fd * 16 + colid;
          const int vo = (((f * 2 + (quad >> 1)) ^ (vr & 7)) * 8) + (quad & 1) * 4;
          vv[ff][fd] = *(const h4*)&Ls[pb][3][vr][vo];
        }
        mk[ff] = *(const fx4*)(maskb + b * SEQ + kb + f * 16 + quad * 4);
      }

      // ---- per q-group: scores^T, online softmax over 32 keys, PV ----
#pragma unroll
      for (int g = 0; g < 2; ++g) {
        float sv[2][4];
#pragma unroll
        for (int ff = 0; ff < 2; ++ff) {
          fx4 ab = __builtin_amdgcn_mfma_f32_16x16x32_bf16(ak[ff][0], bqf[g][0], zero, 0, 0, 0);
          ab = __builtin_amdgcn_mfma_f32_16x16x32_bf16(ak[ff][1], bqf[g][1], ab, 0, 0, 0);
          fx4 tt = __builtin_amdgcn_mfma_f32_16x16x32_bf16(at_[ff][0], btf[g][0], zero, 0, 0, 0);
          tt = __builtin_amdgcn_mfma_f32_16x16x32_bf16(at_[ff][1], btf[g][1], tt, 0, 0, 0);
          fx4 ss = __builtin_amdgcn_mfma_f32_16x16x32_bf16(as_[ff][0], bsf[g][0], zero, 0, 0, 0);
          ss = __builtin_amdgcn_mfma_f32_16x16x32_bf16(as_[ff][1], bsf[g][1], ss, 0, 0, 0);
#pragma unroll
          for (int reg = 0; reg < 4; ++reg)
            sv[ff][reg] = (ab[reg] * tt[reg]) * ss[reg] * rs[g] + mk[ff][reg];
        }

        float bm = sv[0][0];
#pragma unroll
        for (int ff = 0; ff < 2; ++ff)
#pragma unroll
          for (int reg = 0; reg < 4; ++reg) bm = fmaxf(bm, sv[ff][reg]);
        bm = fmaxf(bm, __shfl_xor(bm, 16));
        bm = fmaxf(bm, __shfl_xor(bm, 32));

        // T13 defer-max: rescale only when the tile max exceeds the running
        // max by >8. p is then bounded by e^8 (~2981, fits f16); first tile
        // always rescales (m_ = -1e30). Wave-uniform branch, no divergence.
        if (!__all(bm <= m_[g] + 8.0f)) {
          const float mn = fmaxf(m_[g], bm);
          const float alpha = __expf(m_[g] - mn);
          l_[g] *= alpha;
          m_[g] = mn;
          float ar[4];
#pragma unroll
          for (int reg = 0; reg < 4; ++reg) ar[reg] = __shfl(alpha, quad * 4 + reg);
#pragma unroll
          for (int fd = 0; fd < 4; ++fd)
#pragma unroll
            for (int reg = 0; reg < 4; ++reg) o[g][fd][reg] *= ar[reg];
        }

        const float mloc = m_[g];
        float rsum = 0.f;
        h4 pa[2];
#pragma unroll
        for (int ff = 0; ff < 2; ++ff)
#pragma unroll
          for (int reg = 0; reg < 4; ++reg) {
            const float p = __expf(sv[ff][reg] - mloc);
            rsum += p;
            pa[ff][reg] = (_Float16)p;
          }
        rsum += __shfl_xor(rsum, 16);
        rsum += __shfl_xor(rsum, 32);
        l_[g] += rsum;

#pragma unroll
        for (int ff = 0; ff < 2; ++ff)
#pragma unroll
          for (int fd = 0; fd < 4; ++fd)
            o[g][fd] = __builtin_amdgcn_mfma_f32_16x16x16f16(pa[ff], vv[ff][fd], o[g][fd], 0, 0, 0);
      }
    }
    __syncthreads();
  }

  // Epilogue per group: out[b, s, h*64+d] = O / l  (f32 out).
#pragma unroll
  for (int g = 0; g < 2; ++g) {
    const float linv = 1.0f / l_[g];
    float ir[4];
#pragma unroll
    for (int reg = 0; reg < 4; ++reg) ir[reg] = __shfl(linv, quad * 4 + reg);
#pragma unroll
    for (int reg = 0; reg < 4; ++reg) {
      const int s = q0 + g * 16 + quad * 4 + reg;
#pragma unroll
      for (int fd = 0; fd < 4; ++fd)
        outb[(size_t)(b * SEQ + s) * HDIM + h * DHEAD + fd * 16 + colid] = o[g][fd][reg] * ir[reg];
    }
  }
}

extern "C" void kernel_launch(void* const* d_in, const int* in_sizes, int n_in,
                              void* d_out, int out_size, void* d_ws, size_t ws_size,
                              hipStream_t stream)
{
  (void)in_sizes; (void)n_in; (void)out_size; (void)ws_size;
  const float* hs   = (const float*)d_in[0];
  const float* te   = (const float*)d_in[1];
  const float* se   = (const float*)d_in[2];
  const float* mask = (const float*)d_in[3];
  const float* Wq   = (const float*)d_in[4];
  const float* bq   = (const float*)d_in[5];
  const float* Wk   = (const float*)d_in[6];
  const float* bk   = (const float*)d_in[7];
  const float* Wv   = (const float*)d_in[8];
  const float* bv   = (const float*)d_in[9];
  const float* Wt   = (const float*)d_in[10];
  const float* bt   = (const float*)d_in[11];
  const float* Wsp  = (const float*)d_in[12];
  const float* bsp  = (const float*)d_in[13];
  float* out = (float*)d_out;
  unsigned short* ws = (unsigned short*)d_ws;

  // ws layout (ushort units): Qb@0 Kb@1SZ Tb@2SZ Sb@3SZ Vt(f16)@4SZ
  // convert-phase: hsb@5SZ teb@6SZ seb@7SZ W[5]@8SZ+z*WSZ (dead after proj)
  convert_kernel<<<dim3(1536, 8), 256, 0, stream>>>(hs, te, se, Wq, Wk, Wv, Wt, Wsp, ws);
  proj_kernel<<<dim3(960), 256, 0, stream>>>(ws, bq, bk, bv, bt, bsp);
  attn_kernel<<<dim3(384), 256, 0, stream>>>(ws, mask, out);
}

// Round 10
// 193.971 us; speedup vs baseline: 1.1069x; 1.0004x over previous
//
#include <hip/hip_runtime.h>

#define NHEADS 12
#define SEQ    1024
#define HDIM   768
#define DHEAD  64
#define BH_TOT 48
#define EPSN   1e-6f

typedef __attribute__((ext_vector_type(8))) short    bf8;  // 8 bf16 (4 VGPRs) MFMA A/B frag
typedef __attribute__((ext_vector_type(4))) float    fx4;  // MFMA C/D frag / float4
typedef __attribute__((ext_vector_type(4))) _Float16 h4;   // 4 f16 (2 VGPRs) 16x16x16 frag

#define SZT 3145728u   // 48*1024*64 elements (one head-split tensor)
#define WSZ 589824u    // 768*768 elements (one weight matrix)

__device__ __forceinline__ float bf2f(unsigned short h) {
  union { unsigned int u; float f; } v; v.u = ((unsigned int)h) << 16; return v.f;
}
__device__ __forceinline__ unsigned short f2bf(float f) {
  union { float f; unsigned int u; } v; v.f = f;
  unsigned int u = v.u;
  return (unsigned short)((u + 0x7FFFu + ((u >> 16) & 1u)) >> 16);
}

// async global->LDS, 16B per lane; LDS dest = wave-uniform base + lane*16.
typedef __attribute__((address_space(3))) unsigned int lds_u32;
typedef __attribute__((address_space(1))) const unsigned int glb_u32;
__device__ __forceinline__ void gld16(const unsigned short* g, unsigned short* l) {
  __builtin_amdgcn_global_load_lds((glb_u32*)g, (lds_u32*)l, 16, 0, 0);
}

// ---------------------------------------------------------------------------
// One-shot f32 -> bf16 conversion of X (hs,te,se) and W (q,k,v,t,s) into ws.
// Layout (ushort units): hsb@5SZ teb@6SZ seb@7SZ  W[z]@8SZ + z*WSZ
// ---------------------------------------------------------------------------
__global__ void convert_kernel(const float* __restrict__ hs, const float* __restrict__ te,
                               const float* __restrict__ se,
                               const float* __restrict__ Wq, const float* __restrict__ Wk,
                               const float* __restrict__ Wv, const float* __restrict__ Wt,
                               const float* __restrict__ Ws2,
                               unsigned short* __restrict__ ws)
{
  const int z = blockIdx.y;
  const float* src;
  unsigned short* dst;
  int n;
  if (z < 3) {
    src = (z == 0) ? hs : (z == 1) ? te : se;
    dst = ws + (size_t)(5 + z) * SZT;
    n = 3145728;
  } else {
    src = (z == 3) ? Wq : (z == 4) ? Wk : (z == 5) ? Wv : (z == 6) ? Wt : Ws2;
    dst = ws + (size_t)8 * SZT + (size_t)(z - 3) * WSZ;
    n = 589824;
  }
  const int base = (blockIdx.x * 256 + threadIdx.x) * 8;
  if (base >= n) return;
  const fx4 a = *(const fx4*)(src + base);
  const fx4 b = *(const fx4*)(src + base + 4);
  bf8 o;
#pragma unroll
  for (int j = 0; j < 4; ++j) { o[j] = (short)f2bf(a[j]); o[4 + j] = (short)f2bf(b[j]); }
  *(bf8*)(dst + base) = o;
}

// ---------------------------------------------------------------------------
// Projection GEMM (bf16 in): out = X[4096,768] @ W[768,768]^T + b, head-split.
// XCD-aware 1-D grid 960 (r8). xcd = lin&7 owns y-tiles xcd*4..xcd*4+3 for
// ALL x and z -> same-XCD blocks share X panels (784KB, L2-resident) + W
// panels. z: 0=Q 1=K 2=V(f16, transposed Vt[bh*64+d][1024]) 3=T 4=S
// ---------------------------------------------------------------------------
__global__ __launch_bounds__(256, 3)
void proj_kernel(unsigned short* __restrict__ ws,
                 const float* __restrict__ bq, const float* __restrict__ bk,
                 const float* __restrict__ bv, const float* __restrict__ bt,
                 const float* __restrict__ bs)
{
  __shared__ unsigned short Xs[2][4096];
  __shared__ unsigned short Ys[2][4096];

  // Decode XCD-grouped tile assignment from 1-D block id.
  const int lin = blockIdx.x;          // 0..959
  const int xcd = lin & 7;
  const int idx = lin >> 3;            // 0..119
  const int xt  = idx % 6;             // N-tile
  const int t2  = idx / 6;             // 0..19
  const int yl  = t2 % 4;
  const int z   = t2 / 4;              // 0..4
  const int yt  = xcd * 4 + yl;        // M-tile, grouped per XCD

  const unsigned short* X = ws + (size_t)5 * SZT + (size_t)((z < 3) ? 0 : (z - 2)) * SZT;
  const unsigned short* W = ws + (size_t)8 * SZT + (size_t)z * WSZ;
  const float* bias = (z == 0) ? bq : (z == 1) ? bk : (z == 2) ? bv : (z == 3) ? bt : bs;
  unsigned short* out = ws + (size_t)((z < 2) ? z : (z == 2) ? 4 : (z == 3) ? 2 : 3) * SZT;

  const int tid   = threadIdx.x;
  const int lane  = tid & 63;
  const int wid   = tid >> 6;
  const int wm    = wid >> 1, wn = wid & 1;
  const int colid = lane & 15, quad = lane >> 4;
  const int m0 = yt * 128, n0 = xt * 128;

  auto stage = [&](int kt, int pb) {
#pragma unroll
    for (int i = 0; i < 2; ++i) {
      const int slot = i * 256 + tid;        // 0..511, 16B each
      const int row = slot >> 2, ch = slot & 3;
      gld16(X + (m0 + row) * HDIM + kt + ch * 8, &Xs[pb][slot * 8]);
      gld16(W + (n0 + row) * HDIM + kt + ch * 8, &Ys[pb][slot * 8]);
    }
  };

  fx4 acc[4][4];
#pragma unroll
  for (int i = 0; i < 4; ++i)
#pragma unroll
    for (int j = 0; j < 4; ++j) acc[i][j] = (fx4){0.f, 0.f, 0.f, 0.f};

  stage(0, 0);
  __syncthreads();

  for (int it = 0; it < 24; ++it) {
    const int pb = it & 1;
    if (it + 1 < 24) stage((it + 1) * 32, pb ^ 1);

    bf8 af[4], bfr[4];
#pragma unroll
    for (int i = 0; i < 4; ++i)
      af[i] = *(const bf8*)&Xs[pb][(wm * 64 + i * 16 + colid) * 32 + quad * 8];
#pragma unroll
    for (int j = 0; j < 4; ++j)
      bfr[j] = *(const bf8*)&Ys[pb][(wn * 64 + j * 16 + colid) * 32 + quad * 8];
#pragma unroll
    for (int i = 0; i < 4; ++i)
#pragma unroll
      for (int j = 0; j < 4; ++j)
        acc[i][j] = __builtin_amdgcn_mfma_f32_16x16x32_bf16(af[i], bfr[j], acc[i][j], 0, 0, 0);
    __syncthreads();
  }

  // Epilogue. C/D layout: col=lane&15, row=quad*4+reg.
  if (z != 2) {
#pragma unroll
    for (int i = 0; i < 4; ++i) {
      const int r0 = m0 + wm * 64 + i * 16 + quad * 4;
      const int bb = r0 >> 10, s0 = r0 & 1023;
#pragma unroll
      for (int j = 0; j < 4; ++j) {
        const int c = n0 + wn * 64 + j * 16 + colid;
        const int h = c >> 6, d = c & 63;
        const float bvl = bias[c];
        unsigned short* op = out + (((bb * NHEADS + h) * SEQ + s0) * DHEAD + d);
#pragma unroll
        for (int reg = 0; reg < 4; ++reg)
          op[reg * DHEAD] = f2bf(acc[i][j][reg] + bvl);
      }
    }
  } else {
    // V -> f16, transposed: Vt[(bh*64+d)*1024 + s], 4 consecutive s per 8B store.
#pragma unroll
    for (int i = 0; i < 4; ++i) {
      const int r0 = m0 + wm * 64 + i * 16 + quad * 4;
      const int bb = r0 >> 10, s0 = r0 & 1023;
#pragma unroll
      for (int j = 0; j < 4; ++j) {
        const int c = n0 + wn * 64 + j * 16 + colid;
        const int h = c >> 6, d = c & 63;
        const float bvl = bias[c];
        h4 pk;
#pragma unroll
        for (int reg = 0; reg < 4; ++reg)
          pk[reg] = (_Float16)(acc[i][j][reg] + bvl);
        *(h4*)(void*)(out + ((size_t)((bb * NHEADS + h) * DHEAD + d)) * SEQ + s0) = pk;
      }
    }
  }
}

// ---------------------------------------------------------------------------
// Flash attention. Round 16: r9 (57.8us) + ONE change: deferred-l reduction.
// l is a pure sum of p-values (associative) and the defer-max alpha is
// quad-uniform (derived from the cross-quad-reduced m_), so each lane can
// accumulate only its LOCAL partial sum; the cross-quad xor16+xor32 moves
// from per-unit (128 ds_swizzle ops/thread, ~120cyc LDS-pipe latency each)
// to the epilogue (2 ops total). Halves in-loop cross-lane traffic; frees
// LDS-pipe slots contended with the co-resident wave's frag ds_reads.
// Exact up to ulp reassociation. The bm reduction stays (PV needs a shared
// scale across quads before the MFMA).
// Proven stack: r3 structure + T13 defer-max (r9) + XCD-grouped grids.
// LAWS: (1) q/wave >= 32; (2) don't buy occupancy with VGPR caps or AI;
// (3) no scheduler-fencing intrinsics in the inner loop; (4) one change
// per round.
// ---------------------------------------------------------------------------
__global__ __launch_bounds__(256, 2)
void attn_kernel(const unsigned short* __restrict__ ws,
                 const float* __restrict__ maskb,
                 float* __restrict__ outb)
{
  const unsigned short* Qb  = ws;
  const unsigned short* GT0 = ws + (size_t)1 * SZT;   // K
  const unsigned short* GT1 = ws + (size_t)2 * SZT;   // T
  const unsigned short* GT2 = ws + (size_t)3 * SZT;   // S
  const unsigned short* Vtu = ws + (size_t)4 * SZT;   // V f16 transposed, as ushort

  __shared__ unsigned short Ls[2][4][64][64];  // 64 KB: [buf][K,T,S,V][row][col]

  const int tid   = threadIdx.x;
  const int lane  = tid & 63;
  const int wid   = tid >> 6;          // 0..3
  const int colid = lane & 15, quad = lane >> 4;

  // XCD swizzle: 384 blocks; lin&7 = XCD; each XCD owns 6 bh entirely.
  const int lin = blockIdx.x;
  const int xcd = lin & 7;
  const int idx = lin >> 3;            // 0..47
  const int bh  = xcd * 6 + (idx % 6);
  const int qx  = idx / 6;             // 0..7
  const int b   = bh / NHEADS, h = bh % NHEADS;
  const int q0  = qx * 128 + wid * 32;
  const int base_h = bh * SEQ * DHEAD;

  // Query-side B-frags for 2 q-groups: lane holds B[k=quad*8+j][n=colid].
  bf8 bqf[2][2], btf[2][2], bsf[2][2];
  float rs[2];
#pragma unroll
  for (int g = 0; g < 2; ++g) {
    const int row = q0 + g * 16 + colid;
    const unsigned short* qp = Qb  + base_h + row * 64 + quad * 8;
    const unsigned short* tp = GT1 + base_h + row * 64 + quad * 8;
    const unsigned short* sp = GT2 + base_h + row * 64 + quad * 8;
    bqf[g][0] = *(const bf8*)qp;  bqf[g][1] = *(const bf8*)(qp + 32);
    btf[g][0] = *(const bf8*)tp;  btf[g][1] = *(const bf8*)(tp + 32);
    bsf[g][0] = *(const bf8*)sp;  bsf[g][1] = *(const bf8*)(sp + 32);
    float t2 = 0.f, s2 = 0.f;
#pragma unroll
    for (int fr = 0; fr < 2; ++fr)
#pragma unroll
      for (int j = 0; j < 8; ++j) {
        const float tv = bf2f((unsigned short)btf[g][fr][j]);
        const float sv2 = bf2f((unsigned short)bsf[g][fr][j]);
        t2 += tv * tv; s2 += sv2 * sv2;
      }
    t2 += __shfl_xor(t2, 16); t2 += __shfl_xor(t2, 32);
    s2 += __shfl_xor(s2, 16); s2 += __shfl_xor(s2, 32);
    rs[g] = 1.0f / ((sqrtf(t2) + EPSN) * (sqrtf(s2) + EPSN) * 8.0f);
  }

  // Cooperative staging of one 64-key tile: K,T,S [key][d] bf16 + V [d][key]
  // f16, 8 KB each. 2048 slots of 16B; slot s -> tensor s>>9, row (s>>3)&63,
  // col-slot s&7. Global source pre-swizzled so LDS holds slot^(row&7).
  auto stage = [&](int kb, int pb) {
#pragma unroll
    for (int i = 0; i < 8; ++i) {
      const int s  = i * 256 + tid;
      const int r  = (s >> 3) & 63;
      const int cs = ((s & 7) ^ (r & 7)) * 8;
      unsigned short* dst = &Ls[pb][0][0][0] + s * 8;
      if (i < 2)      gld16(GT0 + base_h + (kb + r) * 64 + cs, dst);
      else if (i < 4) gld16(GT1 + base_h + (kb + r) * 64 + cs, dst);
      else if (i < 6) gld16(GT2 + base_h + (kb + r) * 64 + cs, dst);
      else            gld16(Vtu + ((size_t)(bh * 64 + r)) * 1024 + kb + cs, dst);
    }
  };

  float m_[2], l_[2];
  fx4 o[2][4];
#pragma unroll
  for (int g = 0; g < 2; ++g) {
    m_[g] = -1.0e30f; l_[g] = 0.f;
#pragma unroll
    for (int fd = 0; fd < 4; ++fd) o[g][fd] = (fx4){0.f, 0.f, 0.f, 0.f};
  }
  const fx4 zero = (fx4){0.f, 0.f, 0.f, 0.f};

  stage(0, 0);
  __syncthreads();

#pragma unroll 1
  for (int t = 0; t < 16; ++t) {
    const int pb = t & 1;
    if (t + 1 < 16) stage((t + 1) * 64, pb ^ 1);
    const int kb = t * 64;

#pragma unroll
    for (int hh = 0; hh < 2; ++hh) {
      // ---- 32-key half: frags from LDS (swizzled reads) ----
      bf8 ak[2][2], at_[2][2], as_[2][2];
      h4 vv[2][4];
      fx4 mk[2];
#pragma unroll
      for (int ff = 0; ff < 2; ++ff) {
        const int f   = hh * 2 + ff;
        const int row = f * 16 + colid;
        const int sw  = row & 7;
#pragma unroll
        for (int fr = 0; fr < 2; ++fr) {
          const int co = ((quad + fr * 4) ^ sw) * 8;
          ak[ff][fr]  = *(const bf8*)&Ls[pb][0][row][co];
          at_[ff][fr] = *(const bf8*)&Ls[pb][1][row][co];
          as_[ff][fr] = *(const bf8*)&Ls[pb][2][row][co];
        }
#pragma unroll
        for (int fd = 0; fd < 4; ++fd) {
          const int vr = fd * 16 + colid;
          const int vo = (((f * 2 + (quad >> 1)) ^ (vr & 7)) * 8) + (quad & 1) * 4;
          vv[ff][fd] = *(const h4*)&Ls[pb][3][vr][vo];
        }
        mk[ff] = *(const fx4*)(maskb + b * SEQ + kb + f * 16 + quad * 4);
      }

      // ---- per q-group: scores^T, online softmax over 32 keys, PV ----
#pragma unroll
      for (int g = 0; g < 2; ++g) {
        float sv[2][4];
#pragma unroll
        for (int ff = 0; ff < 2; ++ff) {
          fx4 ab = __builtin_amdgcn_mfma_f32_16x16x32_bf16(ak[ff][0], bqf[g][0], zero, 0, 0, 0);
          ab = __builtin_amdgcn_mfma_f32_16x16x32_bf16(ak[ff][1], bqf[g][1], ab, 0, 0, 0);
          fx4 tt = __builtin_amdgcn_mfma_f32_16x16x32_bf16(at_[ff][0], btf[g][0], zero, 0, 0, 0);
          tt = __builtin_amdgcn_mfma_f32_16x16x32_bf16(at_[ff][1], btf[g][1], tt, 0, 0, 0);
          fx4 ss = __builtin_amdgcn_mfma_f32_16x16x32_bf16(as_[ff][0], bsf[g][0], zero, 0, 0, 0);
          ss = __builtin_amdgcn_mfma_f32_16x16x32_bf16(as_[ff][1], bsf[g][1], ss, 0, 0, 0);
#pragma unroll
          for (int reg = 0; reg < 4; ++reg)
            sv[ff][reg] = (ab[reg] * tt[reg]) * ss[reg] * rs[g] + mk[ff][reg];
        }

        float bm = sv[0][0];
#pragma unroll
        for (int ff = 0; ff < 2; ++ff)
#pragma unroll
          for (int reg = 0; reg < 4; ++reg) bm = fmaxf(bm, sv[ff][reg]);
        bm = fmaxf(bm, __shfl_xor(bm, 16));
        bm = fmaxf(bm, __shfl_xor(bm, 32));

        // T13 defer-max: rescale only when the tile max exceeds the running
        // max by >8. p is then bounded by e^8 (~2981, fits f16); first tile
        // always rescales (m_ = -1e30). Wave-uniform branch, no divergence.
        // alpha is quad-uniform -> scaling the LOCAL l-partial is exact.
        if (!__all(bm <= m_[g] + 8.0f)) {
          const float mn = fmaxf(m_[g], bm);
          const float alpha = __expf(m_[g] - mn);
          l_[g] *= alpha;
          m_[g] = mn;
          float ar[4];
#pragma unroll
          for (int reg = 0; reg < 4; ++reg) ar[reg] = __shfl(alpha, quad * 4 + reg);
#pragma unroll
          for (int fd = 0; fd < 4; ++fd)
#pragma unroll
            for (int reg = 0; reg < 4; ++reg) o[g][fd][reg] *= ar[reg];
        }

        const float mloc = m_[g];
        float rsum = 0.f;
        h4 pa[2];
#pragma unroll
        for (int ff = 0; ff < 2; ++ff)
#pragma unroll
          for (int reg = 0; reg < 4; ++reg) {
            const float p = __expf(sv[ff][reg] - mloc);
            rsum += p;
            pa[ff][reg] = (_Float16)p;
          }
        // Deferred-l: accumulate the LOCAL partial only; cross-quad
        // reduction happens once in the epilogue (saves 128 shfl/thread).
        l_[g] += rsum;

#pragma unroll
        for (int ff = 0; ff < 2; ++ff)
#pragma unroll
          for (int fd = 0; fd < 4; ++fd)
            o[g][fd] = __builtin_amdgcn_mfma_f32_16x16x16f16(pa[ff], vv[ff][fd], o[g][fd], 0, 0, 0);
      }
    }
    __syncthreads();
  }

  // Epilogue per group: reduce l across quads once, then out = O / l.
#pragma unroll
  for (int g = 0; g < 2; ++g) {
    float lt = l_[g];
    lt += __shfl_xor(lt, 16);
    lt += __shfl_xor(lt, 32);
    const float linv = 1.0f / lt;
    float ir[4];
#pragma unroll
    for (int reg = 0; reg < 4; ++reg) ir[reg] = __shfl(linv, quad * 4 + reg);
#pragma unroll
    for (int reg = 0; reg < 4; ++reg) {
      const int s = q0 + g * 16 + quad * 4 + reg;
#pragma unroll
      for (int fd = 0; fd < 4; ++fd)
        outb[(size_t)(b * SEQ + s) * HDIM + h * DHEAD + fd * 16 + colid] = o[g][fd][reg] * ir[reg];
    }
  }
}

extern "C" void kernel_launch(void* const* d_in, const int* in_sizes, int n_in,
                              void* d_out, int out_size, void* d_ws, size_t ws_size,
                              hipStream_t stream)
{
  (void)in_sizes; (void)n_in; (void)out_size; (void)ws_size;
  const float* hs   = (const float*)d_in[0];
  const float* te   = (const float*)d_in[1];
  const float* se   = (const float*)d_in[2];
  const float* mask = (const float*)d_in[3];
  const float* Wq   = (const float*)d_in[4];
  const float* bq   = (const float*)d_in[5];
  const float* Wk   = (const float*)d_in[6];
  const float* bk   = (const float*)d_in[7];
  const float* Wv   = (const float*)d_in[8];
  const float* bv   = (const float*)d_in[9];
  const float* Wt   = (const float*)d_in[10];
  const float* bt   = (const float*)d_in[11];
  const float* Wsp  = (const float*)d_in[12];
  const float* bsp  = (const float*)d_in[13];
  float* out = (float*)d_out;
  unsigned short* ws = (unsigned short*)d_ws;

  // ws layout (ushort units): Qb@0 Kb@1SZ Tb@2SZ Sb@3SZ Vt(f16)@4SZ
  // convert-phase: hsb@5SZ teb@6SZ seb@7SZ W[5]@8SZ+z*WSZ (dead after proj)
  convert_kernel<<<dim3(1536, 8), 256, 0, stream>>>(hs, te, se, Wq, Wk, Wv, Wt, Wsp, ws);
  proj_kernel<<<dim3(960), 256, 0, stream>>>(ws, bq, bk, bv, bt, bsp);
  attn_kernel<<<dim3(384), 256, 0, stream>>>(ws, mask, out);
}

// Round 11
// 191.028 us; speedup vs baseline: 1.1240x; 1.0154x over previous
//
#include <hip/hip_runtime.h>

#define NHEADS 12
#define SEQ    1024
#define HDIM   768
#define DHEAD  64
#define BH_TOT 48
#define EPSN   1e-6f

typedef __attribute__((ext_vector_type(8))) short    bf8;  // 8 bf16 (4 VGPRs) MFMA A/B frag
typedef __attribute__((ext_vector_type(4))) float    fx4;  // MFMA C/D frag / float4
typedef __attribute__((ext_vector_type(4))) _Float16 h4;   // 4 f16 (2 VGPRs) 16x16x16 frag
typedef __attribute__((ext_vector_type(2))) unsigned int u32x2;

#define SZT 3145728u   // 48*1024*64 elements (one head-split tensor)
#define WSZ 589824u    // 768*768 elements (one weight matrix)

__device__ __forceinline__ float bf2f(unsigned short h) {
  union { unsigned int u; float f; } v; v.u = ((unsigned int)h) << 16; return v.f;
}
__device__ __forceinline__ unsigned short f2bf(float f) {
  union { float f; unsigned int u; } v; v.f = f;
  unsigned int u = v.u;
  return (unsigned short)((u + 0x7FFFu + ((u >> 16) & 1u)) >> 16);
}

// Cross-quad max (lane ^16 then ^32) via gfx950 permlane*_swap: VALU ops
// (~4cyc) replacing ds_swizzle (~120cyc LDS-pipe latency) on the softmax
// critical path. swap(x,x) returns (a',b') with per-lane fmax(a',b') =
// max(x[lane], x[lane^K]) -- bit-identical to the __shfl_xor butterfly.
__device__ __forceinline__ float crossmax(float x) {
#if __has_builtin(__builtin_amdgcn_permlane16_swap) && __has_builtin(__builtin_amdgcn_permlane32_swap)
  u32x2 r = __builtin_amdgcn_permlane16_swap(__float_as_uint(x), __float_as_uint(x), false, false);
  x = fmaxf(__uint_as_float(r.x), __uint_as_float(r.y));
  r = __builtin_amdgcn_permlane32_swap(__float_as_uint(x), __float_as_uint(x), false, false);
  x = fmaxf(__uint_as_float(r.x), __uint_as_float(r.y));
#else
  x = fmaxf(x, __shfl_xor(x, 16));
  x = fmaxf(x, __shfl_xor(x, 32));
#endif
  return x;
}

// async global->LDS, 16B per lane; LDS dest = wave-uniform base + lane*16.
typedef __attribute__((address_space(3))) unsigned int lds_u32;
typedef __attribute__((address_space(1))) const unsigned int glb_u32;
__device__ __forceinline__ void gld16(const unsigned short* g, unsigned short* l) {
  __builtin_amdgcn_global_load_lds((glb_u32*)g, (lds_u32*)l, 16, 0, 0);
}

// ---------------------------------------------------------------------------
// One-shot f32 -> bf16 conversion of X (hs,te,se) and W (q,k,v,t,s) into ws.
// Layout (ushort units): hsb@5SZ teb@6SZ seb@7SZ  W[z]@8SZ + z*WSZ
// ---------------------------------------------------------------------------
__global__ void convert_kernel(const float* __restrict__ hs, const float* __restrict__ te,
                               const float* __restrict__ se,
                               const float* __restrict__ Wq, const float* __restrict__ Wk,
                               const float* __restrict__ Wv, const float* __restrict__ Wt,
                               const float* __restrict__ Ws2,
                               unsigned short* __restrict__ ws)
{
  const int z = blockIdx.y;
  const float* src;
  unsigned short* dst;
  int n;
  if (z < 3) {
    src = (z == 0) ? hs : (z == 1) ? te : se;
    dst = ws + (size_t)(5 + z) * SZT;
    n = 3145728;
  } else {
    src = (z == 3) ? Wq : (z == 4) ? Wk : (z == 5) ? Wv : (z == 6) ? Wt : Ws2;
    dst = ws + (size_t)8 * SZT + (size_t)(z - 3) * WSZ;
    n = 589824;
  }
  const int base = (blockIdx.x * 256 + threadIdx.x) * 8;
  if (base >= n) return;
  const fx4 a = *(const fx4*)(src + base);
  const fx4 b = *(const fx4*)(src + base + 4);
  bf8 o;
#pragma unroll
  for (int j = 0; j < 4; ++j) { o[j] = (short)f2bf(a[j]); o[4 + j] = (short)f2bf(b[j]); }
  *(bf8*)(dst + base) = o;
}

// ---------------------------------------------------------------------------
// Projection GEMM (bf16 in): out = X[4096,768] @ W[768,768]^T + b, head-split.
// XCD-aware 1-D grid 960 (r8). xcd = lin&7 owns y-tiles xcd*4..xcd*4+3 for
// ALL x and z -> same-XCD blocks share X panels (784KB, L2-resident) + W
// panels. z: 0=Q 1=K 2=V(f16, transposed Vt[bh*64+d][1024]) 3=T 4=S
// ---------------------------------------------------------------------------
__global__ __launch_bounds__(256, 3)
void proj_kernel(unsigned short* __restrict__ ws,
                 const float* __restrict__ bq, const float* __restrict__ bk,
                 const float* __restrict__ bv, const float* __restrict__ bt,
                 const float* __restrict__ bs)
{
  __shared__ unsigned short Xs[2][4096];
  __shared__ unsigned short Ys[2][4096];

  // Decode XCD-grouped tile assignment from 1-D block id.
  const int lin = blockIdx.x;          // 0..959
  const int xcd = lin & 7;
  const int idx = lin >> 3;            // 0..119
  const int xt  = idx % 6;             // N-tile
  const int t2  = idx / 6;             // 0..19
  const int yl  = t2 % 4;
  const int z   = t2 / 4;              // 0..4
  const int yt  = xcd * 4 + yl;        // M-tile, grouped per XCD

  const unsigned short* X = ws + (size_t)5 * SZT + (size_t)((z < 3) ? 0 : (z - 2)) * SZT;
  const unsigned short* W = ws + (size_t)8 * SZT + (size_t)z * WSZ;
  const float* bias = (z == 0) ? bq : (z == 1) ? bk : (z == 2) ? bv : (z == 3) ? bt : bs;
  unsigned short* out = ws + (size_t)((z < 2) ? z : (z == 2) ? 4 : (z == 3) ? 2 : 3) * SZT;

  const int tid   = threadIdx.x;
  const int lane  = tid & 63;
  const int wid   = tid >> 6;
  const int wm    = wid >> 1, wn = wid & 1;
  const int colid = lane & 15, quad = lane >> 4;
  const int m0 = yt * 128, n0 = xt * 128;

  auto stage = [&](int kt, int pb) {
#pragma unroll
    for (int i = 0; i < 2; ++i) {
      const int slot = i * 256 + tid;        // 0..511, 16B each
      const int row = slot >> 2, ch = slot & 3;
      gld16(X + (m0 + row) * HDIM + kt + ch * 8, &Xs[pb][slot * 8]);
      gld16(W + (n0 + row) * HDIM + kt + ch * 8, &Ys[pb][slot * 8]);
    }
  };

  fx4 acc[4][4];
#pragma unroll
  for (int i = 0; i < 4; ++i)
#pragma unroll
    for (int j = 0; j < 4; ++j) acc[i][j] = (fx4){0.f, 0.f, 0.f, 0.f};

  stage(0, 0);
  __syncthreads();

  for (int it = 0; it < 24; ++it) {
    const int pb = it & 1;
    if (it + 1 < 24) stage((it + 1) * 32, pb ^ 1);

    bf8 af[4], bfr[4];
#pragma unroll
    for (int i = 0; i < 4; ++i)
      af[i] = *(const bf8*)&Xs[pb][(wm * 64 + i * 16 + colid) * 32 + quad * 8];
#pragma unroll
    for (int j = 0; j < 4; ++j)
      bfr[j] = *(const bf8*)&Ys[pb][(wn * 64 + j * 16 + colid) * 32 + quad * 8];
#pragma unroll
    for (int i = 0; i < 4; ++i)
#pragma unroll
      for (int j = 0; j < 4; ++j)
        acc[i][j] = __builtin_amdgcn_mfma_f32_16x16x32_bf16(af[i], bfr[j], acc[i][j], 0, 0, 0);
    __syncthreads();
  }

  // Epilogue. C/D layout: col=lane&15, row=quad*4+reg.
  if (z != 2) {
#pragma unroll
    for (int i = 0; i < 4; ++i) {
      const int r0 = m0 + wm * 64 + i * 16 + quad * 4;
      const int bb = r0 >> 10, s0 = r0 & 1023;
#pragma unroll
      for (int j = 0; j < 4; ++j) {
        const int c = n0 + wn * 64 + j * 16 + colid;
        const int h = c >> 6, d = c & 63;
        const float bvl = bias[c];
        unsigned short* op = out + (((bb * NHEADS + h) * SEQ + s0) * DHEAD + d);
#pragma unroll
        for (int reg = 0; reg < 4; ++reg)
          op[reg * DHEAD] = f2bf(acc[i][j][reg] + bvl);
      }
    }
  } else {
    // V -> f16, transposed: Vt[(bh*64+d)*1024 + s], 4 consecutive s per 8B store.
#pragma unroll
    for (int i = 0; i < 4; ++i) {
      const int r0 = m0 + wm * 64 + i * 16 + quad * 4;
      const int bb = r0 >> 10, s0 = r0 & 1023;
#pragma unroll
      for (int j = 0; j < 4; ++j) {
        const int c = n0 + wn * 64 + j * 16 + colid;
        const int h = c >> 6, d = c & 63;
        const float bvl = bias[c];
        h4 pk;
#pragma unroll
        for (int reg = 0; reg < 4; ++reg)
          pk[reg] = (_Float16)(acc[i][j][reg] + bvl);
        *(h4*)(void*)(out + ((size_t)((bb * NHEADS + h) * DHEAD + d)) * SEQ + s0) = pk;
      }
    }
  }
}

// ---------------------------------------------------------------------------
// Flash attention. Round 17: r10 (53.7us) + ONE change: the in-loop bm
// cross-quad max now uses v_permlane16/32_swap (VALU, ~4cyc) instead of two
// __shfl_xor (ds_swizzle, ~120cyc LDS-pipe each) -- the exp chain waits on
// this max, so it was ~240cyc of serial latency per q-group per unit.
// Bit-identical result; __has_builtin-guarded with shfl fallback.
// Proven stack: r3 structure + T13 defer-max (r9) + deferred-l (r10) +
// XCD-grouped grids (r8).
// LAWS: (1) q/wave >= 32; (2) don't buy occupancy with VGPR caps or AI;
// (3) no scheduler-fencing intrinsics in the inner loop; (4) one change
// per round.
// ---------------------------------------------------------------------------
__global__ __launch_bounds__(256, 2)
void attn_kernel(const unsigned short* __restrict__ ws,
                 const float* __restrict__ maskb,
                 float* __restrict__ outb)
{
  const unsigned short* Qb  = ws;
  const unsigned short* GT0 = ws + (size_t)1 * SZT;   // K
  const unsigned short* GT1 = ws + (size_t)2 * SZT;   // T
  const unsigned short* GT2 = ws + (size_t)3 * SZT;   // S
  const unsigned short* Vtu = ws + (size_t)4 * SZT;   // V f16 transposed, as ushort

  __shared__ unsigned short Ls[2][4][64][64];  // 64 KB: [buf][K,T,S,V][row][col]

  const int tid   = threadIdx.x;
  const int lane  = tid & 63;
  const int wid   = tid >> 6;          // 0..3
  const int colid = lane & 15, quad = lane >> 4;

  // XCD swizzle: 384 blocks; lin&7 = XCD; each XCD owns 6 bh entirely.
  const int lin = blockIdx.x;
  const int xcd = lin & 7;
  const int idx = lin >> 3;            // 0..47
  const int bh  = xcd * 6 + (idx % 6);
  const int qx  = idx / 6;             // 0..7
  const int b   = bh / NHEADS, h = bh % NHEADS;
  const int q0  = qx * 128 + wid * 32;
  const int base_h = bh * SEQ * DHEAD;

  // Query-side B-frags for 2 q-groups: lane holds B[k=quad*8+j][n=colid].
  bf8 bqf[2][2], btf[2][2], bsf[2][2];
  float rs[2];
#pragma unroll
  for (int g = 0; g < 2; ++g) {
    const int row = q0 + g * 16 + colid;
    const unsigned short* qp = Qb  + base_h + row * 64 + quad * 8;
    const unsigned short* tp = GT1 + base_h + row * 64 + quad * 8;
    const unsigned short* sp = GT2 + base_h + row * 64 + quad * 8;
    bqf[g][0] = *(const bf8*)qp;  bqf[g][1] = *(const bf8*)(qp + 32);
    btf[g][0] = *(const bf8*)tp;  btf[g][1] = *(const bf8*)(tp + 32);
    bsf[g][0] = *(const bf8*)sp;  bsf[g][1] = *(const bf8*)(sp + 32);
    float t2 = 0.f, s2 = 0.f;
#pragma unroll
    for (int fr = 0; fr < 2; ++fr)
#pragma unroll
      for (int j = 0; j < 8; ++j) {
        const float tv = bf2f((unsigned short)btf[g][fr][j]);
        const float sv2 = bf2f((unsigned short)bsf[g][fr][j]);
        t2 += tv * tv; s2 += sv2 * sv2;
      }
    t2 += __shfl_xor(t2, 16); t2 += __shfl_xor(t2, 32);
    s2 += __shfl_xor(s2, 16); s2 += __shfl_xor(s2, 32);
    rs[g] = 1.0f / ((sqrtf(t2) + EPSN) * (sqrtf(s2) + EPSN) * 8.0f);
  }

  // Cooperative staging of one 64-key tile: K,T,S [key][d] bf16 + V [d][key]
  // f16, 8 KB each. 2048 slots of 16B; slot s -> tensor s>>9, row (s>>3)&63,
  // col-slot s&7. Global source pre-swizzled so LDS holds slot^(row&7).
  auto stage = [&](int kb, int pb) {
#pragma unroll
    for (int i = 0; i < 8; ++i) {
      const int s  = i * 256 + tid;
      const int r  = (s >> 3) & 63;
      const int cs = ((s & 7) ^ (r & 7)) * 8;
      unsigned short* dst = &Ls[pb][0][0][0] + s * 8;
      if (i < 2)      gld16(GT0 + base_h + (kb + r) * 64 + cs, dst);
      else if (i < 4) gld16(GT1 + base_h + (kb + r) * 64 + cs, dst);
      else if (i < 6) gld16(GT2 + base_h + (kb + r) * 64 + cs, dst);
      else            gld16(Vtu + ((size_t)(bh * 64 + r)) * 1024 + kb + cs, dst);
    }
  };

  float m_[2], l_[2];
  fx4 o[2][4];
#pragma unroll
  for (int g = 0; g < 2; ++g) {
    m_[g] = -1.0e30f; l_[g] = 0.f;
#pragma unroll
    for (int fd = 0; fd < 4; ++fd) o[g][fd] = (fx4){0.f, 0.f, 0.f, 0.f};
  }
  const fx4 zero = (fx4){0.f, 0.f, 0.f, 0.f};

  stage(0, 0);
  __syncthreads();

#pragma unroll 1
  for (int t = 0; t < 16; ++t) {
    const int pb = t & 1;
    if (t + 1 < 16) stage((t + 1) * 64, pb ^ 1);
    const int kb = t * 64;

#pragma unroll
    for (int hh = 0; hh < 2; ++hh) {
      // ---- 32-key half: frags from LDS (swizzled reads) ----
      bf8 ak[2][2], at_[2][2], as_[2][2];
      h4 vv[2][4];
      fx4 mk[2];
#pragma unroll
      for (int ff = 0; ff < 2; ++ff) {
        const int f   = hh * 2 + ff;
        const int row = f * 16 + colid;
        const int sw  = row & 7;
#pragma unroll
        for (int fr = 0; fr < 2; ++fr) {
          const int co = ((quad + fr * 4) ^ sw) * 8;
          ak[ff][fr]  = *(const bf8*)&Ls[pb][0][row][co];
          at_[ff][fr] = *(const bf8*)&Ls[pb][1][row][co];
          as_[ff][fr] = *(const bf8*)&Ls[pb][2][row][co];
        }
#pragma unroll
        for (int fd = 0; fd < 4; ++fd) {
          const int vr = fd * 16 + colid;
          const int vo = (((f * 2 + (quad >> 1)) ^ (vr & 7)) * 8) + (quad & 1) * 4;
          vv[ff][fd] = *(const h4*)&Ls[pb][3][vr][vo];
        }
        mk[ff] = *(const fx4*)(maskb + b * SEQ + kb + f * 16 + quad * 4);
      }

      // ---- per q-group: scores^T, online softmax over 32 keys, PV ----
#pragma unroll
      for (int g = 0; g < 2; ++g) {
        float sv[2][4];
#pragma unroll
        for (int ff = 0; ff < 2; ++ff) {
          fx4 ab = __builtin_amdgcn_mfma_f32_16x16x32_bf16(ak[ff][0], bqf[g][0], zero, 0, 0, 0);
          ab = __builtin_amdgcn_mfma_f32_16x16x32_bf16(ak[ff][1], bqf[g][1], ab, 0, 0, 0);
          fx4 tt = __builtin_amdgcn_mfma_f32_16x16x32_bf16(at_[ff][0], btf[g][0], zero, 0, 0, 0);
          tt = __builtin_amdgcn_mfma_f32_16x16x32_bf16(at_[ff][1], btf[g][1], tt, 0, 0, 0);
          fx4 ss = __builtin_amdgcn_mfma_f32_16x16x32_bf16(as_[ff][0], bsf[g][0], zero, 0, 0, 0);
          ss = __builtin_amdgcn_mfma_f32_16x16x32_bf16(as_[ff][1], bsf[g][1], ss, 0, 0, 0);
#pragma unroll
          for (int reg = 0; reg < 4; ++reg)
            sv[ff][reg] = (ab[reg] * tt[reg]) * ss[reg] * rs[g] + mk[ff][reg];
        }

        float bm = sv[0][0];
#pragma unroll
        for (int ff = 0; ff < 2; ++ff)
#pragma unroll
          for (int reg = 0; reg < 4; ++reg) bm = fmaxf(bm, sv[ff][reg]);
        bm = crossmax(bm);   // permlane16/32_swap: VALU, was 2x ds_swizzle

        // T13 defer-max: rescale only when the tile max exceeds the running
        // max by >8. p is then bounded by e^8 (~2981, fits f16); first tile
        // always rescales (m_ = -1e30). Wave-uniform branch, no divergence.
        // alpha is quad-uniform -> scaling the LOCAL l-partial is exact.
        if (!__all(bm <= m_[g] + 8.0f)) {
          const float mn = fmaxf(m_[g], bm);
          const float alpha = __expf(m_[g] - mn);
          l_[g] *= alpha;
          m_[g] = mn;
          float ar[4];
#pragma unroll
          for (int reg = 0; reg < 4; ++reg) ar[reg] = __shfl(alpha, quad * 4 + reg);
#pragma unroll
          for (int fd = 0; fd < 4; ++fd)
#pragma unroll
            for (int reg = 0; reg < 4; ++reg) o[g][fd][reg] *= ar[reg];
        }

        const float mloc = m_[g];
        float rsum = 0.f;
        h4 pa[2];
#pragma unroll
        for (int ff = 0; ff < 2; ++ff)
#pragma unroll
          for (int reg = 0; reg < 4; ++reg) {
            const float p = __expf(sv[ff][reg] - mloc);
            rsum += p;
            pa[ff][reg] = (_Float16)p;
          }
        // Deferred-l: accumulate the LOCAL partial only; cross-quad
        // reduction happens once in the epilogue (saves 128 shfl/thread).
        l_[g] += rsum;

#pragma unroll
        for (int ff = 0; ff < 2; ++ff)
#pragma unroll
          for (int fd = 0; fd < 4; ++fd)
            o[g][fd] = __builtin_amdgcn_mfma_f32_16x16x16f16(pa[ff], vv[ff][fd], o[g][fd], 0, 0, 0);
      }
    }
    __syncthreads();
  }

  // Epilogue per group: reduce l across quads once, then out = O / l.
#pragma unroll
  for (int g = 0; g < 2; ++g) {
    float lt = l_[g];
    lt += __shfl_xor(lt, 16);
    lt += __shfl_xor(lt, 32);
    const float linv = 1.0f / lt;
    float ir[4];
#pragma unroll
    for (int reg = 0; reg < 4; ++reg) ir[reg] = __shfl(linv, quad * 4 + reg);
#pragma unroll
    for (int reg = 0; reg < 4; ++reg) {
      const int s = q0 + g * 16 + quad * 4 + reg;
#pragma unroll
      for (int fd = 0; fd < 4; ++fd)
        outb[(size_t)(b * SEQ + s) * HDIM + h * DHEAD + fd * 16 + colid] = o[g][fd][reg] * ir[reg];
    }
  }
}

extern "C" void kernel_launch(void* const* d_in, const int* in_sizes, int n_in,
                              void* d_out, int out_size, void* d_ws, size_t ws_size,
                              hipStream_t stream)
{
  (void)in_sizes; (void)n_in; (void)out_size; (void)ws_size;
  const float* hs   = (const float*)d_in[0];
  const float* te   = (const float*)d_in[1];
  const float* se   = (const float*)d_in[2];
  const float* mask = (const float*)d_in[3];
  const float* Wq   = (const float*)d_in[4];
  const float* bq   = (const float*)d_in[5];
  const float* Wk   = (const float*)d_in[6];
  const float* bk   = (const float*)d_in[7];
  const float* Wv   = (const float*)d_in[8];
  const float* bv   = (const float*)d_in[9];
  const float* Wt   = (const float*)d_in[10];
  const float* bt   = (const float*)d_in[11];
  const float* Wsp  = (const float*)d_in[12];
  const float* bsp  = (const float*)d_in[13];
  float* out = (float*)d_out;
  unsigned short* ws = (unsigned short*)d_ws;

  // ws layout (ushort units): Qb@0 Kb@1SZ Tb@2SZ Sb@3SZ Vt(f16)@4SZ
  // convert-phase: hsb@5SZ teb@6SZ seb@7SZ W[5]@8SZ+z*WSZ (dead after proj)
  convert_kernel<<<dim3(1536, 8), 256, 0, stream>>>(hs, te, se, Wq, Wk, Wv, Wt, Wsp, ws);
  proj_kernel<<<dim3(960), 256, 0, stream>>>(ws, bq, bk, bv, bt, bsp);
  attn_kernel<<<dim3(384), 256, 0, stream>>>(ws, mask, out);
}